// Round 2
// 543.327 us; speedup vs baseline: 1.1964x; 1.1964x over previous
//
#include <hip/hip_runtime.h>
#include <stdint.h>

// ---------------------------------------------------------------------------
// Decoder block: emb-gather+affine -> causal conv(K=3) -> relu -> GLU(softmax)
//                -> map matmul (+) cross-attention (QK^T softmax PV)
// Shapes: V=50257 E=256 H=256 2H=512 K=3 T=1024 B=32 S=1024 L=1023
// Output: (32, 1023, 512) f32
// R5 == R4 resubmit (round-1 bench died in container acquisition, no kernel
// signal): conv as m97-style 128x128xBK32 GEMM with global_load_lds dbuf
// staging (zero-scratch causal boundary); attn with cross-phase register
// prefetch (V 2-kt deep, enc 2-kk deep, next-iter loads issued pre-barrier),
// lgkmcnt-only raw s_barrier in the main loop, setprio around MFMA clusters.
// Workspace layout (bytes):
//   Xbf   [32][1024][512] bf16 @ 0          (33,554,432)
//   Ybf   [32][1024][512] bf16 @ 33554432   (33,554,432)
//   dec   [32][1024][256] bf16 @ 67108864   (16,777,216)  (first 1KB = zero
//                                            scratch for conv boundary; glu
//                                            overwrites the whole buffer)
//   encb  [32][1024][256] bf16 @ 83886080   (16,777,216)
//   vtb   [32][512][1024] bf16 @ 100663296  (33,554,432)  (V transposed)
//   wcb   [512][1536]     bf16 @ 134217728  ( 1,572,864)
//   mwb   [512][256]      bf16 @ 135790592  (   262,144)
//   awb   [512][256]      bf16 @ 136052736  (   262,144)
// ---------------------------------------------------------------------------

typedef __bf16 bf16x8_t __attribute__((ext_vector_type(8)));
typedef float  f32x4_t  __attribute__((ext_vector_type(4)));

#define DEV __device__ __forceinline__

DEV unsigned short f2bf(float f) {
  union { float f; unsigned u; } v; v.f = f;
  unsigned r = v.u + 0x7fffu + ((v.u >> 16) & 1u);
  return (unsigned short)(r >> 16);
}
DEV float bf2f(unsigned short u) {
  union { unsigned u; float f; } v; v.u = ((unsigned)u) << 16;
  return v.f;
}

DEV void gload_lds16(const void* g, void* l) {
  __builtin_amdgcn_global_load_lds((const __attribute__((address_space(1))) void*)g,
                                   (__attribute__((address_space(3))) void*)l, 16, 0, 0);
}

// barrier that drains only LDS ops — register-destined global loads stay in
// flight across it (the whole point of the cross-phase prefetch).
DEV void barrier_lgkm() {
  asm volatile("s_waitcnt lgkmcnt(0)" ::: "memory");
  __builtin_amdgcn_s_barrier();
}

// -------------------------- zero scratch -----------------------------------
__global__ void zero_k(unsigned short* p) { p[threadIdx.x] = 0; }

// -------------------------- f32 -> bf16 copy -------------------------------
__global__ __launch_bounds__(256) void cvt_bf16_k(const float* __restrict__ src,
                                                  unsigned short* __restrict__ dst,
                                                  int n) {
  int i = (blockIdx.x * 256 + threadIdx.x) * 4;
  if (i >= n) return;
  float4 v = *(const float4*)(src + i);
  ushort4 o;
  o.x = f2bf(v.x); o.y = f2bf(v.y); o.z = f2bf(v.z); o.w = f2bf(v.w);
  *(ushort4*)(dst + i) = o;
}

// ------------------- V: f32 [b][s][d] -> bf16 [b][d][s] --------------------
__global__ __launch_bounds__(256) void cvt_transpose_v_k(const float* __restrict__ src,
                                                         unsigned short* __restrict__ dst) {
  __shared__ float tile[32][33];
  int b = blockIdx.z, s0 = blockIdx.x * 32, d0 = blockIdx.y * 32;
  int tx = threadIdx.x & 31, ty = threadIdx.x >> 5;
  const float* p = src + ((size_t)b * 1024 + s0) * 512 + d0;
  for (int r = ty; r < 32; r += 8) tile[r][tx] = p[(size_t)r * 512 + tx];
  __syncthreads();
  unsigned short* q = dst + ((size_t)b * 512 + d0) * 1024 + s0;
  for (int r = ty; r < 32; r += 8) q[(size_t)r * 1024 + tx] = f2bf(tile[tx][r]);
}

// ------ X[b][t][c] = bf16( emb[target[t,b]] @ affine_w^T + affine_b ) ------
__global__ __launch_bounds__(256) void embed_affine_k(const int* __restrict__ tgt,
                                                      const float* __restrict__ emb,
                                                      const unsigned short* __restrict__ awb,
                                                      const float* __restrict__ ab,
                                                      unsigned short* __restrict__ X) {
  constexpr int AP = 264;
  __shared__ unsigned short xs[32 * AP];
  const int r0 = blockIdx.x * 32;
  const int tid = threadIdx.x;
  for (int idx = tid; idx < 32 * 64; idx += 256) {
    int r = idx >> 6, c4 = (idx & 63) * 4;
    int row = tgt[r0 + r];
    float4 v = *(const float4*)&emb[(size_t)row * 256 + c4];
    ushort4 o;
    o.x = f2bf(v.x); o.y = f2bf(v.y); o.z = f2bf(v.z); o.w = f2bf(v.w);
    *(ushort4*)&xs[r * AP + c4] = o;
  }
  __syncthreads();
  const int lane = tid & 63, w = tid >> 6, q = lane >> 4, ln = lane & 15;
  f32x4_t acc[2][8];
#pragma unroll
  for (int mt = 0; mt < 2; ++mt)
#pragma unroll
    for (int nt = 0; nt < 8; ++nt) acc[mt][nt] = (f32x4_t){0.f, 0.f, 0.f, 0.f};
  for (int kk = 0; kk < 256; kk += 32) {
    bf16x8_t a[2], bb[8];
#pragma unroll
    for (int mt = 0; mt < 2; ++mt)
      a[mt] = *(const bf16x8_t*)(xs + (mt * 16 + ln) * AP + kk + q * 8);
#pragma unroll
    for (int nt = 0; nt < 8; ++nt) {
      int n = ((w * 8 + nt) << 4) + ln;
      bb[nt] = *(const bf16x8_t*)(awb + ((size_t)n << 8) + kk + q * 8);
    }
#pragma unroll
    for (int mt = 0; mt < 2; ++mt)
#pragma unroll
      for (int nt = 0; nt < 8; ++nt)
        acc[mt][nt] = __builtin_amdgcn_mfma_f32_16x16x32_bf16(a[mt], bb[nt], acc[mt][nt], 0, 0, 0);
  }
#pragma unroll
  for (int nt = 0; nt < 8; ++nt) {
    const int o = ((w * 8 + nt) << 4) + ln;
    const float bias = ab[o];
#pragma unroll
    for (int mt = 0; mt < 2; ++mt)
#pragma unroll
      for (int r = 0; r < 4; ++r) {
        int rid = r0 + mt * 16 + q * 4 + r;
        int t = rid >> 5, b = rid & 31;
        X[(((size_t)(b * 1024 + t)) << 9) + o] = f2bf(acc[mt][nt][r] + bias);
      }
  }
}

// ---------------------------------------------------------------------------
// conv as tiled GEMM (m97 structure): C[128 l][128 o] per block, K=1536,
// BK=32, double-buffered LDS tiles staged with global_load_lds (16B).
// A[l][k = i*512+c] = X[b][l-2+i][c]; i = kk>>9 is constant within a BK slice.
// Causal boundary (l-2+i < 0): per-lane source pointer redirected to a 1KB
// zero scratch (global_load_lds sources are per-lane; LDS dest stays linear).
// ---------------------------------------------------------------------------
DEV void cstage(unsigned short* AsB, unsigned short* BsB,
                const unsigned short* __restrict__ X,
                const unsigned short* __restrict__ Wc,
                const unsigned short* __restrict__ zbuf,
                int b, int l0, int n0, int t, int w, int srow, int scolg) {
  const int kk = t << 5;
  const int i  = kk >> 9;
  const int c0 = kk & 511;
  // A rows 0..63  (only place lr can go negative)
  {
    const int lr = l0 + srow + i - 2;
    const unsigned short* sp = (lr < 0)
        ? (zbuf + scolg * 8)
        : (X + (((size_t)(b * 1024 + lr)) << 9) + c0 + scolg * 8);
    gload_lds16(sp, AsB + w * 512);
  }
  // A rows 64..127 (never negative)
  {
    const int lr = l0 + 64 + srow + i - 2;
    gload_lds16(X + (((size_t)(b * 1024 + lr)) << 9) + c0 + scolg * 8,
                AsB + 2048 + w * 512);
  }
  // B = Wc rows n0..n0+127
  gload_lds16(Wc + (size_t)(n0 + srow) * 1536 + kk + scolg * 8, BsB + w * 512);
  gload_lds16(Wc + (size_t)(n0 + 64 + srow) * 1536 + kk + scolg * 8,
              BsB + 2048 + w * 512);
}

__global__ __launch_bounds__(256) void conv_gemm_k(const unsigned short* __restrict__ X,
                                                   const unsigned short* __restrict__ Wc,
                                                   const float* __restrict__ cb,
                                                   const unsigned short* __restrict__ zbuf,
                                                   unsigned short* __restrict__ Y) {
  __shared__ unsigned short As[2][4096];  // [128 rows][32 k] bf16, x2 dbuf
  __shared__ unsigned short Bs[2][4096];
  const int bid = blockIdx.x;
  const int mtile = bid >> 2;           // 0..255
  const int b  = mtile >> 3;            // 0..31
  const int l0 = (mtile & 7) << 7;      // 0..896
  const int n0 = (bid & 3) << 7;        // 0..384
  const int tid = threadIdx.x;
  const int w = tid >> 6, lane = tid & 63, q = lane >> 4, ln = lane & 15;
  const int wr = w >> 1, wc = w & 1;    // wave -> 64x64 quadrant
  const int srow = tid >> 2, scolg = tid & 3;

  f32x4_t acc[4][4];
#pragma unroll
  for (int mt = 0; mt < 4; ++mt)
#pragma unroll
    for (int nt = 0; nt < 4; ++nt) acc[mt][nt] = (f32x4_t){0.f, 0.f, 0.f, 0.f};

  cstage(As[0], Bs[0], X, Wc, zbuf, b, l0, n0, 0, w, srow, scolg);
  __syncthreads();  // vmcnt(0) drain: tile 0 landed

  for (int t = 0; t < 48; ++t) {
    const int cur = t & 1;
    if (t < 47)
      cstage(As[cur ^ 1], Bs[cur ^ 1], X, Wc, zbuf, b, l0, n0, t + 1, w, srow, scolg);
    const unsigned short* Ab = As[cur];
    const unsigned short* Bb = Bs[cur];
    bf16x8_t af[4], bf[4];
#pragma unroll
    for (int x = 0; x < 4; ++x) {
      af[x] = *(const bf16x8_t*)(Ab + (wr * 64 + x * 16 + ln) * 32 + q * 8);
      bf[x] = *(const bf16x8_t*)(Bb + (wc * 64 + x * 16 + ln) * 32 + q * 8);
    }
#pragma unroll
    for (int mt = 0; mt < 4; ++mt)
#pragma unroll
      for (int nt = 0; nt < 4; ++nt)
        acc[mt][nt] = __builtin_amdgcn_mfma_f32_16x16x32_bf16(af[mt], bf[nt], acc[mt][nt], 0, 0, 0);
    __syncthreads();  // drains next-tile staging + all waves done reading cur
  }

#pragma unroll
  for (int nt = 0; nt < 4; ++nt) {
    const int o = n0 + wc * 64 + nt * 16 + ln;
    const float bias = cb[o];
#pragma unroll
    for (int mt = 0; mt < 4; ++mt)
#pragma unroll
      for (int r = 0; r < 4; ++r) {
        const int l = l0 + wr * 64 + mt * 16 + q * 4 + r;
        float v = acc[mt][nt][r] + bias;
        Y[(((size_t)b * 1024 + l) << 9) + o] = f2bf(v > 0.f ? v : 0.f);
      }
  }
}

// ---- GLU: dec[b][l][h] = A[h] * softmax_h(Bg)[h], one wave per (b,l) row ---
__global__ __launch_bounds__(256) void glu_k(const unsigned short* __restrict__ Y,
                                             unsigned short* __restrict__ dec) {
  const int row = blockIdx.x * 4 + (threadIdx.x >> 6);
  const int lane = threadIdx.x & 63;
  const unsigned short* p = Y + ((size_t)row << 9);
  ushort4 av = *(const ushort4*)(p + lane * 4);
  ushort4 gv = *(const ushort4*)(p + 256 + lane * 4);
  float e0 = __expf(bf2f(gv.x)), e1 = __expf(bf2f(gv.y));
  float e2 = __expf(bf2f(gv.z)), e3 = __expf(bf2f(gv.w));
  float s = e0 + e1 + e2 + e3;
#pragma unroll
  for (int off = 32; off > 0; off >>= 1) s += __shfl_xor(s, off);
  float inv = 1.f / s;
  ushort4 o;
  o.x = f2bf(bf2f(av.x) * e0 * inv);
  o.y = f2bf(bf2f(av.y) * e1 * inv);
  o.z = f2bf(bf2f(av.z) * e2 * inv);
  o.w = f2bf(bf2f(av.w) * e3 * inv);
  *(ushort4*)(dec + ((size_t)row << 8) + lane * 4) = o;
}

// ---------------------------------------------------------------------------
// Fused attention + map epilogue. Cross-phase register prefetch:
//   V frags double-buffered 2-kt deep (next-iter kt0/kt1 issued before the
//   barrier), enc frags double-buffered 2-kk deep (next-iter kk0/kk1 issued
//   during QKT tail -> in flight across exp+barrier+PV).
// In-loop barrier is lgkmcnt-only: register-destined prefetches are NOT
// drained (only the LDS P-exchange needs ordering).
// ---------------------------------------------------------------------------
constexpr int QPc = 264;  // Q LDS stride (bf16)
constexpr int PPc = 136;  // P LDS stride (bf16)

DEV void loadv(bf16x8_t (&dst)[8], const unsigned short* __restrict__ vtB,
               int w, int ln, int q, int soff) {
#pragma unroll
  for (int nt = 0; nt < 8; ++nt)
    dst[nt] = *(const bf16x8_t*)(vtB + (((size_t)((w << 7) + nt * 16 + ln)) << 10) + soff + q * 8);
}
DEV void loade(bf16x8_t (&dst)[2], const unsigned short* __restrict__ encB,
               int srow, int kk, int ln, int q) {
#pragma unroll
  for (int nt = 0; nt < 2; ++nt)
    dst[nt] = *(const bf16x8_t*)(encB + (((size_t)(srow + nt * 16 + ln)) << 8) + kk + q * 8);
}
DEV void qkt_step(f32x4_t (&sacc)[2][2], const unsigned short* qs, int kk,
                  int ln, int q, const bf16x8_t (&eb)[2]) {
  bf16x8_t a0 = *(const bf16x8_t*)(qs + ln * QPc + kk + q * 8);
  bf16x8_t a1 = *(const bf16x8_t*)(qs + (16 + ln) * QPc + kk + q * 8);
  __builtin_amdgcn_s_setprio(1);
  sacc[0][0] = __builtin_amdgcn_mfma_f32_16x16x32_bf16(a0, eb[0], sacc[0][0], 0, 0, 0);
  sacc[0][1] = __builtin_amdgcn_mfma_f32_16x16x32_bf16(a0, eb[1], sacc[0][1], 0, 0, 0);
  sacc[1][0] = __builtin_amdgcn_mfma_f32_16x16x32_bf16(a1, eb[0], sacc[1][0], 0, 0, 0);
  sacc[1][1] = __builtin_amdgcn_mfma_f32_16x16x32_bf16(a1, eb[1], sacc[1][1], 0, 0, 0);
  __builtin_amdgcn_s_setprio(0);
}
DEV void pv_step(f32x4_t (&acc)[2][8], const unsigned short* pb, int kt,
                 int ln, int q, const bf16x8_t (&vb)[8]) {
  bf16x8_t a0 = *(const bf16x8_t*)(pb + ln * PPc + kt * 32 + q * 8);
  bf16x8_t a1 = *(const bf16x8_t*)(pb + (16 + ln) * PPc + kt * 32 + q * 8);
  __builtin_amdgcn_s_setprio(1);
#pragma unroll
  for (int nt = 0; nt < 8; ++nt) {
    acc[0][nt] = __builtin_amdgcn_mfma_f32_16x16x32_bf16(a0, vb[nt], acc[0][nt], 0, 0, 0);
    acc[1][nt] = __builtin_amdgcn_mfma_f32_16x16x32_bf16(a1, vb[nt], acc[1][nt], 0, 0, 0);
  }
  __builtin_amdgcn_s_setprio(0);
}

__global__ __launch_bounds__(256, 2) void attn_fused_k(const unsigned short* __restrict__ dec,
                                                       const unsigned short* __restrict__ enc,
                                                       const unsigned short* __restrict__ vt,
                                                       const unsigned short* __restrict__ mw,
                                                       const float* __restrict__ mb,
                                                       float* __restrict__ out) {
  __shared__ unsigned short qs[32 * QPc];
  __shared__ unsigned short ps[2][32 * PPc];
  __shared__ float rws[4][32];
  __shared__ float rinv_s[32];

  const int bi = blockIdx.x;
  const int j = bi >> 3;
  const int b = ((bi & 7) << 2) | (j >> 5);  // same b -> same XCD
  const int l0 = (j & 31) << 5;
  const int tid = threadIdx.x;
  const int w = tid >> 6, lane = tid & 63, q = lane >> 4, ln = lane & 15;

  // stage Q = dec[b][l0:l0+32][0:256] into LDS (bf16)
  for (int idx = tid; idx < 32 * 32; idx += 256) {
    int r = idx >> 5, c8 = (idx & 31) * 8;
    *(uint4*)&qs[r * QPc + c8] =
        *(const uint4*)(dec + (((size_t)b * 1024 + l0 + r) << 8) + c8);
  }
  __syncthreads();

  f32x4_t acc[2][8];
#pragma unroll
  for (int mt = 0; mt < 2; ++mt)
#pragma unroll
    for (int nt = 0; nt < 8; ++nt) acc[mt][nt] = (f32x4_t){0.f, 0.f, 0.f, 0.f};
  float prow[2][4];
#pragma unroll
  for (int mt = 0; mt < 2; ++mt)
#pragma unroll
    for (int r = 0; r < 4; ++r) prow[mt][r] = 0.f;

  const unsigned short* encB = enc + ((size_t)b << 18);  // [s][256]
  const unsigned short* vtB  = vt + ((size_t)b << 19);   // [d][1024]

  // prologue prefetch (issued AFTER the qs barrier so nothing drains them)
  bf16x8_t vA[8], vB[8], eA[2], eB[2];
  loadv(vA, vtB, w, ln, q, 0);
  loadv(vB, vtB, w, ln, q, 32);
  loade(eA, encB, w << 5, 0, ln, q);
  loade(eB, encB, w << 5, 32, ln, q);

  for (int it = 0; it < 8; ++it) {
    const int s0 = it << 7;
    const int sw = s0 + (w << 5);   // this wave's 32-s strip
    const int swn = sw + 128;       // next iter's strip (overruns stay in ws)
    f32x4_t sacc[2][2];
#pragma unroll
    for (int mt = 0; mt < 2; ++mt)
#pragma unroll
      for (int nt = 0; nt < 2; ++nt) sacc[mt][nt] = (f32x4_t){0.f, 0.f, 0.f, 0.f};

    // ---- QK^T, 8 steps; each consumes one prefetched enc pair and reloads
    //      it 2 steps ahead; steps 6/7 prefetch NEXT iter's kk0/kk1 ----
    qkt_step(sacc, qs,   0, ln, q, eA); loade(eA, encB, sw,  64, ln, q);
    qkt_step(sacc, qs,  32, ln, q, eB); loade(eB, encB, sw,  96, ln, q);
    qkt_step(sacc, qs,  64, ln, q, eA); loade(eA, encB, sw, 128, ln, q);
    qkt_step(sacc, qs,  96, ln, q, eB); loade(eB, encB, sw, 160, ln, q);
    qkt_step(sacc, qs, 128, ln, q, eA); loade(eA, encB, sw, 192, ln, q);
    qkt_step(sacc, qs, 160, ln, q, eB); loade(eB, encB, sw, 224, ln, q);
    qkt_step(sacc, qs, 192, ln, q, eA); loade(eA, encB, swn,  0, ln, q);
    qkt_step(sacc, qs, 224, ln, q, eB); loade(eB, encB, swn, 32, ln, q);

    // ---- exp (f32), rowsum partials, P -> LDS ----
    unsigned short* pb = ps[it & 1];
#pragma unroll
    for (int mt = 0; mt < 2; ++mt)
#pragma unroll
      for (int nt = 0; nt < 2; ++nt)
#pragma unroll
        for (int r = 0; r < 4; ++r) {
          float e = __expf(sacc[mt][nt][r]);
          prow[mt][r] += e;
          pb[(mt * 16 + q * 4 + r) * PPc + (w << 5) + nt * 16 + ln] = f2bf(e);
        }
    barrier_lgkm();  // LDS-only drain: eA/eB/vA/vB prefetches stay in flight

    // ---- PV: each kt consumes a prefetched V buffer, reloads 2 kt ahead
    //      (kt2/kt3 prefetch NEXT iter's kt0/kt1 across the barrier) ----
    pv_step(acc, pb, 0, ln, q, vA); loadv(vA, vtB, w, ln, q, s0 + 64);
    pv_step(acc, pb, 1, ln, q, vB); loadv(vB, vtB, w, ln, q, s0 + 96);
    pv_step(acc, pb, 2, ln, q, vA); loadv(vA, vtB, w, ln, q, s0 + 128);
    pv_step(acc, pb, 3, ln, q, vB); loadv(vB, vtB, w, ln, q, s0 + 160);
  }

  // ---- rowsum: reduce per-lane partials over the 16 ln lanes ----
#pragma unroll
  for (int mt = 0; mt < 2; ++mt)
#pragma unroll
    for (int r = 0; r < 4; ++r) {
      float v = prow[mt][r];
      v += __shfl_xor(v, 1); v += __shfl_xor(v, 2);
      v += __shfl_xor(v, 4); v += __shfl_xor(v, 8);
      if (ln == 0) rws[w][mt * 16 + q * 4 + r] = v;
    }
  __syncthreads();
  if (tid < 32)
    rinv_s[tid] = 1.f / (rws[0][tid] + rws[1][tid] + rws[2][tid] + rws[3][tid]);
  __syncthreads();

  float ri[2][4];
#pragma unroll
  for (int mt = 0; mt < 2; ++mt)
#pragma unroll
    for (int r = 0; r < 4; ++r) ri[mt][r] = rinv_s[mt * 16 + q * 4 + r];
#pragma unroll
  for (int mt = 0; mt < 2; ++mt)
#pragma unroll
    for (int nt = 0; nt < 8; ++nt)
#pragma unroll
      for (int r = 0; r < 4; ++r) acc[mt][nt][r] *= ri[mt][r];

  // ---- map epilogue: acc += dec_tile @ map_w^T (A-frags from qs) ----
  for (int kk = 0; kk < 256; kk += 32) {
    bf16x8_t a[2], bb[8];
#pragma unroll
    for (int mt = 0; mt < 2; ++mt)
      a[mt] = *(const bf16x8_t*)(qs + (mt * 16 + ln) * QPc + kk + q * 8);
#pragma unroll
    for (int nt = 0; nt < 8; ++nt) {
      int n = (w << 7) + nt * 16 + ln;
      bb[nt] = *(const bf16x8_t*)(mw + ((size_t)n << 8) + kk + q * 8);
    }
#pragma unroll
    for (int mt = 0; mt < 2; ++mt)
#pragma unroll
      for (int nt = 0; nt < 8; ++nt)
        acc[mt][nt] = __builtin_amdgcn_mfma_f32_16x16x32_bf16(a[mt], bb[nt], acc[mt][nt], 0, 0, 0);
  }

  // ---- store out (f32), skipping l == 1023 ----
#pragma unroll
  for (int nt = 0; nt < 8; ++nt) {
    const int d = (w << 7) + nt * 16 + ln;
    const float bias = mb[d];
#pragma unroll
    for (int mt = 0; mt < 2; ++mt)
#pragma unroll
      for (int r = 0; r < 4; ++r) {
        int l = l0 + mt * 16 + q * 4 + r;
        if (l < 1023) out[((size_t)b * 1023 + l) * 512 + d] = acc[mt][nt][r] + bias;
      }
  }
}

// ---------------------------------------------------------------------------
extern "C" void kernel_launch(void* const* d_in, const int* in_sizes, int n_in,
                              void* d_out, int out_size, void* d_ws, size_t ws_size,
                              hipStream_t stream) {
  const int*   target = (const int*)d_in[1];
  const float* enc    = (const float*)d_in[2];
  const float* src    = (const float*)d_in[3];
  const float* emb    = (const float*)d_in[4];
  const float* aw     = (const float*)d_in[5];
  const float* ab     = (const float*)d_in[6];
  const float* cw     = (const float*)d_in[7];
  const float* cb     = (const float*)d_in[8];
  const float* mw     = (const float*)d_in[9];
  const float* mb     = (const float*)d_in[10];
  float* out = (float*)d_out;
  char* ws = (char*)d_ws;

  unsigned short* Xbf  = (unsigned short*)(ws);
  unsigned short* Ybf  = (unsigned short*)(ws + 33554432);
  unsigned short* dec  = (unsigned short*)(ws + 67108864);
  unsigned short* encb = (unsigned short*)(ws + 83886080);
  unsigned short* vtb  = (unsigned short*)(ws + 100663296);
  unsigned short* wcb  = (unsigned short*)(ws + 134217728);
  unsigned short* mwb  = (unsigned short*)(ws + 135790592);
  unsigned short* awb  = (unsigned short*)(ws + 136052736);

  zero_k<<<1, 512, 0, stream>>>(dec);  // 1KB zero scratch (glu overwrites later)
  cvt_bf16_k<<<8192, 256, 0, stream>>>(enc, encb, 32 * 1024 * 256);
  cvt_bf16_k<<<768, 256, 0, stream>>>(cw, wcb, 512 * 1536);
  cvt_bf16_k<<<128, 256, 0, stream>>>(mw, mwb, 512 * 256);
  cvt_bf16_k<<<128, 256, 0, stream>>>(aw, awb, 512 * 256);
  cvt_transpose_v_k<<<dim3(32, 16, 32), 256, 0, stream>>>(src, vtb);
  embed_affine_k<<<1024, 256, 0, stream>>>(target, emb, awb, ab, Xbf);
  conv_gemm_k<<<1024, 256, 0, stream>>>(Xbf, wcb, cb, dec, Ybf);
  glu_k<<<8192, 256, 0, stream>>>(Ybf, dec);
  attn_fused_k<<<1024, 256, 0, stream>>>(dec, encb, vtb, mwb, mb, out);
}

// Round 4
// 452.464 us; speedup vs baseline: 1.4366x; 1.2008x over previous
//
#include <hip/hip_runtime.h>
#include <stdint.h>

// ---------------------------------------------------------------------------
// Decoder block: emb-gather+affine -> causal conv(K=3) -> relu -> GLU(softmax)
//                -> map matmul (+) cross-attention (QK^T softmax PV)
// Shapes: V=50257 E=256 H=256 2H=512 K=3 T=1024 B=32 S=1024 L=1023
// Output: (32, 1023, 512) f32
// R7 == R6 resubmit (round-3 bench died in container acquisition, no kernel
// signal; same infra error as round 1 which passed on identical resubmit).
// Attention decomposed into two plain GEMMs (no max-subtraction needed):
//   attn_s_k : P = exp(dec @ enc^T), bf16, M=32768 N=1024 K=256; rowsums via
//              wave-reduce + atomicAdd. P overwrites dead Xbf+Ybf (64MB, L3).
//   attn_pv_k: out = (P @ V^T) * rinv + dec @ map_w^T + bias,
//              M=32768 N=512 K=1024(+256 map chunk), rinv at phase boundary.
// Both clone the verified conv_gemm_k 128x128xBK32 global_load_lds structure.
// Workspace layout (bytes):
//   Xbf   [32][1024][512] bf16 @ 0          (33,554,432)  \ P [32768][1024]
//   Ybf   [32][1024][512] bf16 @ 33554432   (33,554,432)  / bf16 after glu
//   dec   [32][1024][256] bf16 @ 67108864   (16,777,216)  (first 1KB = zero
//                                            scratch for conv boundary; glu
//                                            overwrites the whole buffer)
//   encb  [32][1024][256] bf16 @ 83886080   (16,777,216)
//   vtb   [32][512][1024] bf16 @ 100663296  (33,554,432)  (V transposed)
//   wcb   [512][1536]     bf16 @ 134217728  ( 1,572,864)  (first 128KB reused
//                                            as f32 rowsums after conv)
//   mwb   [512][256]      bf16 @ 135790592  (   262,144)
//   awb   [512][256]      bf16 @ 136052736  (   262,144)
// ---------------------------------------------------------------------------

typedef __bf16 bf16x8_t __attribute__((ext_vector_type(8)));
typedef float  f32x4_t  __attribute__((ext_vector_type(4)));

#define DEV __device__ __forceinline__

DEV unsigned short f2bf(float f) {
  union { float f; unsigned u; } v; v.f = f;
  unsigned r = v.u + 0x7fffu + ((v.u >> 16) & 1u);
  return (unsigned short)(r >> 16);
}
DEV float bf2f(unsigned short u) {
  union { unsigned u; float f; } v; v.u = ((unsigned)u) << 16;
  return v.f;
}

DEV void gload_lds16(const void* g, void* l) {
  __builtin_amdgcn_global_load_lds((const __attribute__((address_space(1))) void*)g,
                                   (__attribute__((address_space(3))) void*)l, 16, 0, 0);
}

// -------------------------- zero helpers -----------------------------------
__global__ void zero_k(unsigned short* p) { p[threadIdx.x] = 0; }

__global__ __launch_bounds__(256) void zero_rows_k(float* p) {
  int i = (blockIdx.x * 256 + threadIdx.x) * 4;
  *(float4*)(p + i) = make_float4(0.f, 0.f, 0.f, 0.f);
}

// -------------------------- f32 -> bf16 copy -------------------------------
__global__ __launch_bounds__(256) void cvt_bf16_k(const float* __restrict__ src,
                                                  unsigned short* __restrict__ dst,
                                                  int n) {
  int i = (blockIdx.x * 256 + threadIdx.x) * 4;
  if (i >= n) return;
  float4 v = *(const float4*)(src + i);
  ushort4 o;
  o.x = f2bf(v.x); o.y = f2bf(v.y); o.z = f2bf(v.z); o.w = f2bf(v.w);
  *(ushort4*)(dst + i) = o;
}

// ------------------- V: f32 [b][s][d] -> bf16 [b][d][s] --------------------
__global__ __launch_bounds__(256) void cvt_transpose_v_k(const float* __restrict__ src,
                                                         unsigned short* __restrict__ dst) {
  __shared__ float tile[32][33];
  int b = blockIdx.z, s0 = blockIdx.x * 32, d0 = blockIdx.y * 32;
  int tx = threadIdx.x & 31, ty = threadIdx.x >> 5;
  const float* p = src + ((size_t)b * 1024 + s0) * 512 + d0;
  for (int r = ty; r < 32; r += 8) tile[r][tx] = p[(size_t)r * 512 + tx];
  __syncthreads();
  unsigned short* q = dst + ((size_t)b * 512 + d0) * 1024 + s0;
  for (int r = ty; r < 32; r += 8) q[(size_t)r * 1024 + tx] = f2bf(tile[tx][r]);
}

// ------ X[b][t][c] = bf16( emb[target[t,b]] @ affine_w^T + affine_b ) ------
__global__ __launch_bounds__(256) void embed_affine_k(const int* __restrict__ tgt,
                                                      const float* __restrict__ emb,
                                                      const unsigned short* __restrict__ awb,
                                                      const float* __restrict__ ab,
                                                      unsigned short* __restrict__ X) {
  constexpr int AP = 264;
  __shared__ unsigned short xs[32 * AP];
  const int r0 = blockIdx.x * 32;
  const int tid = threadIdx.x;
  for (int idx = tid; idx < 32 * 64; idx += 256) {
    int r = idx >> 6, c4 = (idx & 63) * 4;
    int row = tgt[r0 + r];
    float4 v = *(const float4*)&emb[(size_t)row * 256 + c4];
    ushort4 o;
    o.x = f2bf(v.x); o.y = f2bf(v.y); o.z = f2bf(v.z); o.w = f2bf(v.w);
    *(ushort4*)&xs[r * AP + c4] = o;
  }
  __syncthreads();
  const int lane = tid & 63, w = tid >> 6, q = lane >> 4, ln = lane & 15;
  f32x4_t acc[2][8];
#pragma unroll
  for (int mt = 0; mt < 2; ++mt)
#pragma unroll
    for (int nt = 0; nt < 8; ++nt) acc[mt][nt] = (f32x4_t){0.f, 0.f, 0.f, 0.f};
  for (int kk = 0; kk < 256; kk += 32) {
    bf16x8_t a[2], bb[8];
#pragma unroll
    for (int mt = 0; mt < 2; ++mt)
      a[mt] = *(const bf16x8_t*)(xs + (mt * 16 + ln) * AP + kk + q * 8);
#pragma unroll
    for (int nt = 0; nt < 8; ++nt) {
      int n = ((w * 8 + nt) << 4) + ln;
      bb[nt] = *(const bf16x8_t*)(awb + ((size_t)n << 8) + kk + q * 8);
    }
#pragma unroll
    for (int mt = 0; mt < 2; ++mt)
#pragma unroll
      for (int nt = 0; nt < 8; ++nt)
        acc[mt][nt] = __builtin_amdgcn_mfma_f32_16x16x32_bf16(a[mt], bb[nt], acc[mt][nt], 0, 0, 0);
  }
#pragma unroll
  for (int nt = 0; nt < 8; ++nt) {
    const int o = ((w * 8 + nt) << 4) + ln;
    const float bias = ab[o];
#pragma unroll
    for (int mt = 0; mt < 2; ++mt)
#pragma unroll
      for (int r = 0; r < 4; ++r) {
        int rid = r0 + mt * 16 + q * 4 + r;
        int t = rid >> 5, b = rid & 31;
        X[(((size_t)(b * 1024 + t)) << 9) + o] = f2bf(acc[mt][nt][r] + bias);
      }
  }
}

// ---------------------------------------------------------------------------
// conv as tiled GEMM (m97 structure): C[128 l][128 o] per block, K=1536,
// BK=32, double-buffered LDS tiles staged with global_load_lds (16B).
// ---------------------------------------------------------------------------
DEV void cstage(unsigned short* AsB, unsigned short* BsB,
                const unsigned short* __restrict__ X,
                const unsigned short* __restrict__ Wc,
                const unsigned short* __restrict__ zbuf,
                int b, int l0, int n0, int t, int w, int srow, int scolg) {
  const int kk = t << 5;
  const int i  = kk >> 9;
  const int c0 = kk & 511;
  {
    const int lr = l0 + srow + i - 2;
    const unsigned short* sp = (lr < 0)
        ? (zbuf + scolg * 8)
        : (X + (((size_t)(b * 1024 + lr)) << 9) + c0 + scolg * 8);
    gload_lds16(sp, AsB + w * 512);
  }
  {
    const int lr = l0 + 64 + srow + i - 2;
    gload_lds16(X + (((size_t)(b * 1024 + lr)) << 9) + c0 + scolg * 8,
                AsB + 2048 + w * 512);
  }
  gload_lds16(Wc + (size_t)(n0 + srow) * 1536 + kk + scolg * 8, BsB + w * 512);
  gload_lds16(Wc + (size_t)(n0 + 64 + srow) * 1536 + kk + scolg * 8,
              BsB + 2048 + w * 512);
}

__global__ __launch_bounds__(256) void conv_gemm_k(const unsigned short* __restrict__ X,
                                                   const unsigned short* __restrict__ Wc,
                                                   const float* __restrict__ cb,
                                                   const unsigned short* __restrict__ zbuf,
                                                   unsigned short* __restrict__ Y) {
  __shared__ unsigned short As[2][4096];
  __shared__ unsigned short Bs[2][4096];
  const int bid = blockIdx.x;
  const int mtile = bid >> 2;
  const int b  = mtile >> 3;
  const int l0 = (mtile & 7) << 7;
  const int n0 = (bid & 3) << 7;
  const int tid = threadIdx.x;
  const int w = tid >> 6, lane = tid & 63, q = lane >> 4, ln = lane & 15;
  const int wr = w >> 1, wc = w & 1;
  const int srow = tid >> 2, scolg = tid & 3;

  f32x4_t acc[4][4];
#pragma unroll
  for (int mt = 0; mt < 4; ++mt)
#pragma unroll
    for (int nt = 0; nt < 4; ++nt) acc[mt][nt] = (f32x4_t){0.f, 0.f, 0.f, 0.f};

  cstage(As[0], Bs[0], X, Wc, zbuf, b, l0, n0, 0, w, srow, scolg);
  __syncthreads();

  for (int t = 0; t < 48; ++t) {
    const int cur = t & 1;
    if (t < 47)
      cstage(As[cur ^ 1], Bs[cur ^ 1], X, Wc, zbuf, b, l0, n0, t + 1, w, srow, scolg);
    const unsigned short* Ab = As[cur];
    const unsigned short* Bb = Bs[cur];
    bf16x8_t af[4], bf[4];
#pragma unroll
    for (int x = 0; x < 4; ++x) {
      af[x] = *(const bf16x8_t*)(Ab + (wr * 64 + x * 16 + ln) * 32 + q * 8);
      bf[x] = *(const bf16x8_t*)(Bb + (wc * 64 + x * 16 + ln) * 32 + q * 8);
    }
#pragma unroll
    for (int mt = 0; mt < 4; ++mt)
#pragma unroll
      for (int nt = 0; nt < 4; ++nt)
        acc[mt][nt] = __builtin_amdgcn_mfma_f32_16x16x32_bf16(af[mt], bf[nt], acc[mt][nt], 0, 0, 0);
    __syncthreads();
  }

#pragma unroll
  for (int nt = 0; nt < 4; ++nt) {
    const int o = n0 + wc * 64 + nt * 16 + ln;
    const float bias = cb[o];
#pragma unroll
    for (int mt = 0; mt < 4; ++mt)
#pragma unroll
      for (int r = 0; r < 4; ++r) {
        const int l = l0 + wr * 64 + mt * 16 + q * 4 + r;
        float v = acc[mt][nt][r] + bias;
        Y[(((size_t)b * 1024 + l) << 9) + o] = f2bf(v > 0.f ? v : 0.f);
      }
  }
}

// ---- GLU: dec[b][l][h] = A[h] * softmax_h(Bg)[h], one wave per (b,l) row ---
__global__ __launch_bounds__(256) void glu_k(const unsigned short* __restrict__ Y,
                                             unsigned short* __restrict__ dec) {
  const int row = blockIdx.x * 4 + (threadIdx.x >> 6);
  const int lane = threadIdx.x & 63;
  const unsigned short* p = Y + ((size_t)row << 9);
  ushort4 av = *(const ushort4*)(p + lane * 4);
  ushort4 gv = *(const ushort4*)(p + 256 + lane * 4);
  float e0 = __expf(bf2f(gv.x)), e1 = __expf(bf2f(gv.y));
  float e2 = __expf(bf2f(gv.z)), e3 = __expf(bf2f(gv.w));
  float s = e0 + e1 + e2 + e3;
#pragma unroll
  for (int off = 32; off > 0; off >>= 1) s += __shfl_xor(s, off);
  float inv = 1.f / s;
  ushort4 o;
  o.x = f2bf(bf2f(av.x) * e0 * inv);
  o.y = f2bf(bf2f(av.y) * e1 * inv);
  o.z = f2bf(bf2f(av.z) * e2 * inv);
  o.w = f2bf(bf2f(av.w) * e3 * inv);
  *(ushort4*)(dec + ((size_t)row << 8) + lane * 4) = o;
}

// ---------------------------------------------------------------------------
// Generic 128x128 tile staging for row-major A [*][strideA], B [*][strideB].
// ---------------------------------------------------------------------------
DEV void gstage(unsigned short* AsB, unsigned short* BsB,
                const unsigned short* __restrict__ Arow,
                const unsigned short* __restrict__ Brow,
                int strideA, int strideB, int kk, int w, int srow, int scolg) {
  gload_lds16(Arow + (size_t)srow * strideA + kk + scolg * 8, AsB + w * 512);
  gload_lds16(Arow + (size_t)(64 + srow) * strideA + kk + scolg * 8,
              AsB + 2048 + w * 512);
  gload_lds16(Brow + (size_t)srow * strideB + kk + scolg * 8, BsB + w * 512);
  gload_lds16(Brow + (size_t)(64 + srow) * strideB + kk + scolg * 8,
              BsB + 2048 + w * 512);
}

// ---------------------------------------------------------------------------
// attn GEMM1: P[row][s] = exp( dec[row] . enc_b[s] ), rowsum atomics.
// M=32768 (b*1024+l), N=1024 (s), K=256. Grid 2048, XCD-swizzled.
// ---------------------------------------------------------------------------
__global__ __launch_bounds__(256) void attn_s_k(const unsigned short* __restrict__ dec,
                                                const unsigned short* __restrict__ enc,
                                                unsigned short* __restrict__ P,
                                                float* __restrict__ rows) {
  __shared__ unsigned short As[2][4096];
  __shared__ unsigned short Bs[2][4096];
  const int bid = blockIdx.x;
  const int wg = ((bid & 7) << 8) + (bid >> 3);  // bijective: 2048 % 8 == 0
  const int ntile = wg & 7, mtile = wg >> 3;     // same-b wgs -> same XCD
  const int b = mtile >> 3;
  const int row0 = mtile << 7;
  const int s0 = ntile << 7;
  const int tid = threadIdx.x;
  const int w = tid >> 6, lane = tid & 63, q = lane >> 4, ln = lane & 15;
  const int wr = w >> 1, wc = w & 1;
  const int srow = tid >> 2, scolg = tid & 3;

  const unsigned short* Ab = dec + ((size_t)row0 << 8);                    // [128][256]
  const unsigned short* Bb = enc + ((size_t)b << 18) + ((size_t)s0 << 8);  // [128][256]

  f32x4_t acc[4][4];
#pragma unroll
  for (int mt = 0; mt < 4; ++mt)
#pragma unroll
    for (int nt = 0; nt < 4; ++nt) acc[mt][nt] = (f32x4_t){0.f, 0.f, 0.f, 0.f};

  gstage(As[0], Bs[0], Ab, Bb, 256, 256, 0, w, srow, scolg);
  __syncthreads();

  for (int t = 0; t < 8; ++t) {
    const int cur = t & 1;
    if (t < 7)
      gstage(As[cur ^ 1], Bs[cur ^ 1], Ab, Bb, 256, 256, (t + 1) << 5, w, srow, scolg);
    const unsigned short* Ap = As[cur];
    const unsigned short* Bp = Bs[cur];
    bf16x8_t af[4], bf[4];
#pragma unroll
    for (int x = 0; x < 4; ++x) {
      af[x] = *(const bf16x8_t*)(Ap + (wr * 64 + x * 16 + ln) * 32 + q * 8);
      bf[x] = *(const bf16x8_t*)(Bp + (wc * 64 + x * 16 + ln) * 32 + q * 8);
    }
#pragma unroll
    for (int mt = 0; mt < 4; ++mt)
#pragma unroll
      for (int nt = 0; nt < 4; ++nt)
        acc[mt][nt] = __builtin_amdgcn_mfma_f32_16x16x32_bf16(af[mt], bf[nt], acc[mt][nt], 0, 0, 0);
    __syncthreads();
  }

  // epilogue: exp -> bf16 P store; f32 rowsum partials -> wave reduce -> atomic
  float rs[4][4];
#pragma unroll
  for (int mt = 0; mt < 4; ++mt)
#pragma unroll
    for (int r = 0; r < 4; ++r) rs[mt][r] = 0.f;
#pragma unroll
  for (int nt = 0; nt < 4; ++nt) {
    const int col = s0 + wc * 64 + nt * 16 + ln;
#pragma unroll
    for (int mt = 0; mt < 4; ++mt)
#pragma unroll
      for (int r = 0; r < 4; ++r) {
        const int row = row0 + wr * 64 + mt * 16 + q * 4 + r;
        float e = __expf(acc[mt][nt][r]);
        rs[mt][r] += e;
        P[((size_t)row << 10) + col] = f2bf(e);
      }
  }
#pragma unroll
  for (int mt = 0; mt < 4; ++mt)
#pragma unroll
    for (int r = 0; r < 4; ++r) {
      float v = rs[mt][r];
      v += __shfl_xor(v, 1); v += __shfl_xor(v, 2);
      v += __shfl_xor(v, 4); v += __shfl_xor(v, 8);
      if (ln == 0)
        atomicAdd(&rows[row0 + wr * 64 + mt * 16 + q * 4 + r], v);
    }
}

// ---------------------------------------------------------------------------
// attn GEMM2: out[row][d] = (P[row] . V^T[d]) * rinv[row] + dec[row] . mw[d]
//             + mb[d].  M=32768, N=512, K = 1024 (s) then 256 (map chunk).
// rinv scaling applied at the K-phase boundary (t==31). Grid 1024.
// ---------------------------------------------------------------------------
__global__ __launch_bounds__(256) void attn_pv_k(const unsigned short* __restrict__ P,
                                                 const unsigned short* __restrict__ vt,
                                                 const unsigned short* __restrict__ dec,
                                                 const unsigned short* __restrict__ mw,
                                                 const float* __restrict__ rows,
                                                 const float* __restrict__ mb,
                                                 float* __restrict__ out) {
  __shared__ unsigned short As[2][4096];
  __shared__ unsigned short Bs[2][4096];
  const int bid = blockIdx.x;
  const int wg = ((bid & 7) << 7) + (bid >> 3);  // bijective: 1024 % 8 == 0
  const int ntile = wg & 3, mtile = wg >> 2;
  const int b = mtile >> 3;
  const int row0 = mtile << 7;
  const int d0 = ntile << 7;
  const int tid = threadIdx.x;
  const int w = tid >> 6, lane = tid & 63, q = lane >> 4, ln = lane & 15;
  const int wr = w >> 1, wc = w & 1;
  const int srow = tid >> 2, scolg = tid & 3;

  const unsigned short* A1 = P + ((size_t)row0 << 10);                    // [128][1024]
  const unsigned short* B1 = vt + ((size_t)b << 19) + ((size_t)d0 << 10); // [128][1024]
  const unsigned short* A2 = dec + ((size_t)row0 << 8);                   // [128][256]
  const unsigned short* B2 = mw + ((size_t)d0 << 8);                      // [128][256]

  // rinv (rowsums are final: previous kernel finished)
  float rinv[4][4];
#pragma unroll
  for (int mt = 0; mt < 4; ++mt)
#pragma unroll
    for (int r = 0; r < 4; ++r)
      rinv[mt][r] = 1.f / rows[row0 + wr * 64 + mt * 16 + q * 4 + r];

  f32x4_t acc[4][4];
#pragma unroll
  for (int mt = 0; mt < 4; ++mt)
#pragma unroll
    for (int nt = 0; nt < 4; ++nt) acc[mt][nt] = (f32x4_t){0.f, 0.f, 0.f, 0.f};

  gstage(As[0], Bs[0], A1, B1, 1024, 1024, 0, w, srow, scolg);
  __syncthreads();

  for (int t = 0; t < 40; ++t) {
    const int cur = t & 1;
    if (t < 39) {
      const int tn = t + 1;
      if (tn < 32)
        gstage(As[cur ^ 1], Bs[cur ^ 1], A1, B1, 1024, 1024, tn << 5, w, srow, scolg);
      else
        gstage(As[cur ^ 1], Bs[cur ^ 1], A2, B2, 256, 256, (tn - 32) << 5, w, srow, scolg);
    }
    const unsigned short* Ap = As[cur];
    const unsigned short* Bp = Bs[cur];
    bf16x8_t af[4], bf[4];
#pragma unroll
    for (int x = 0; x < 4; ++x) {
      af[x] = *(const bf16x8_t*)(Ap + (wr * 64 + x * 16 + ln) * 32 + q * 8);
      bf[x] = *(const bf16x8_t*)(Bp + (wc * 64 + x * 16 + ln) * 32 + q * 8);
    }
#pragma unroll
    for (int mt = 0; mt < 4; ++mt)
#pragma unroll
      for (int nt = 0; nt < 4; ++nt)
        acc[mt][nt] = __builtin_amdgcn_mfma_f32_16x16x32_bf16(af[mt], bf[nt], acc[mt][nt], 0, 0, 0);
    if (t == 31) {
      // PV phase done: normalize by rowsum before map chunk accumulates
#pragma unroll
      for (int mt = 0; mt < 4; ++mt)
#pragma unroll
        for (int nt = 0; nt < 4; ++nt)
#pragma unroll
          for (int r = 0; r < 4; ++r) acc[mt][nt][r] *= rinv[mt][r];
    }
    __syncthreads();
  }

  // epilogue: + bias, store f32, skip l == 1023
#pragma unroll
  for (int nt = 0; nt < 4; ++nt) {
    const int d = d0 + wc * 64 + nt * 16 + ln;
    const float bias = mb[d];
#pragma unroll
    for (int mt = 0; mt < 4; ++mt)
#pragma unroll
      for (int r = 0; r < 4; ++r) {
        const int row = row0 + wr * 64 + mt * 16 + q * 4 + r;
        const int l = row & 1023;
        if (l < 1023)
          out[((size_t)b * 1023 + l) * 512 + d] = acc[mt][nt][r] + bias;
      }
  }
}

// ---------------------------------------------------------------------------
extern "C" void kernel_launch(void* const* d_in, const int* in_sizes, int n_in,
                              void* d_out, int out_size, void* d_ws, size_t ws_size,
                              hipStream_t stream) {
  const int*   target = (const int*)d_in[1];
  const float* enc    = (const float*)d_in[2];
  const float* src    = (const float*)d_in[3];
  const float* emb    = (const float*)d_in[4];
  const float* aw     = (const float*)d_in[5];
  const float* ab     = (const float*)d_in[6];
  const float* cw     = (const float*)d_in[7];
  const float* cb     = (const float*)d_in[8];
  const float* mw     = (const float*)d_in[9];
  const float* mb     = (const float*)d_in[10];
  float* out = (float*)d_out;
  char* ws = (char*)d_ws;

  unsigned short* Xbf  = (unsigned short*)(ws);            // P aliases Xbf+Ybf
  unsigned short* Ybf  = (unsigned short*)(ws + 33554432);
  unsigned short* Pb   = (unsigned short*)(ws);            // [32768][1024] bf16
  unsigned short* dec  = (unsigned short*)(ws + 67108864);
  unsigned short* encb = (unsigned short*)(ws + 83886080);
  unsigned short* vtb  = (unsigned short*)(ws + 100663296);
  unsigned short* wcb  = (unsigned short*)(ws + 134217728);
  float*          rows = (float*)(ws + 134217728);         // reuses wcb post-conv
  unsigned short* mwb  = (unsigned short*)(ws + 135790592);
  unsigned short* awb  = (unsigned short*)(ws + 136052736);

  zero_k<<<1, 512, 0, stream>>>(dec);  // 1KB zero scratch for conv boundary
  cvt_bf16_k<<<8192, 256, 0, stream>>>(enc, encb, 32 * 1024 * 256);
  cvt_bf16_k<<<768, 256, 0, stream>>>(cw, wcb, 512 * 1536);
  cvt_bf16_k<<<128, 256, 0, stream>>>(mw, mwb, 512 * 256);
  cvt_bf16_k<<<128, 256, 0, stream>>>(aw, awb, 512 * 256);
  cvt_transpose_v_k<<<dim3(32, 16, 32), 256, 0, stream>>>(src, vtb);
  embed_affine_k<<<1024, 256, 0, stream>>>(target, emb, awb, ab, Xbf);
  conv_gemm_k<<<1024, 256, 0, stream>>>(Xbf, wcb, cb, dec, Ybf);
  zero_rows_k<<<32, 256, 0, stream>>>(rows);   // wcb dead after conv
  glu_k<<<8192, 256, 0, stream>>>(Ybf, dec);
  attn_s_k<<<2048, 256, 0, stream>>>(dec, encb, Pb, rows);
  attn_pv_k<<<1024, 256, 0, stream>>>(Pb, vtb, dec, mwb, rows, mb, out);
}

// Round 5
// 440.561 us; speedup vs baseline: 1.4754x; 1.0270x over previous
//
#include <hip/hip_runtime.h>
#include <stdint.h>

// ---------------------------------------------------------------------------
// Decoder block: emb-gather+affine -> causal conv(K=3) -> relu -> GLU(softmax)
//                -> map matmul (+) cross-attention (QK^T softmax PV)
// Shapes: V=50257 E=256 H=256 2H=512 K=3 T=1024 B=32 S=1024 L=1023
// Output: (32, 1023, 512) f32
// R8: all three GEMM kernels upgraded:
//   - BK 32 -> 64 (32 MFMA per barrier pair instead of 16)
//   - counted s_waitcnt vmcnt(8): next-tile global_load_lds stay in flight
//     across the stage-ready barrier (T4-minimum); lgkmcnt(0)+barrier after
//     MFMA protects the buffer overwritten next iteration.
//   - both-sides XOR granule swizzle (p ^= row&7): linear gload_lds dest,
//     inverse-swizzled GLOBAL source granule, swizzled frag-read address.
//     Kills the 8-way (BK32) / 16-way (BK64 unswizzled) bank conflict.
//   - conv grid remap: all 4 n-tiles of an m-tile share an XCD (A L2 reuse).
// Workspace layout (bytes):
//   Xbf   [32][1024][512] bf16 @ 0          (33,554,432)  \ P [32768][1024]
//   Ybf   [32][1024][512] bf16 @ 33554432   (33,554,432)  / bf16 after glu
//   dec   [32][1024][256] bf16 @ 67108864   (16,777,216)  (first 1KB = zero
//                                            scratch for conv boundary)
//   encb  [32][1024][256] bf16 @ 83886080   (16,777,216)
//   vtb   [32][512][1024] bf16 @ 100663296  (33,554,432)  (V transposed)
//   wcb   [512][1536]     bf16 @ 134217728  ( 1,572,864)  (first 128KB reused
//                                            as f32 rowsums after conv)
//   mwb   [512][256]      bf16 @ 135790592  (   262,144)
//   awb   [512][256]      bf16 @ 136052736  (   262,144)
// ---------------------------------------------------------------------------

typedef __bf16 bf16x8_t __attribute__((ext_vector_type(8)));
typedef float  f32x4_t  __attribute__((ext_vector_type(4)));

#define DEV __device__ __forceinline__

DEV unsigned short f2bf(float f) {
  union { float f; unsigned u; } v; v.f = f;
  unsigned r = v.u + 0x7fffu + ((v.u >> 16) & 1u);
  return (unsigned short)(r >> 16);
}
DEV float bf2f(unsigned short u) {
  union { unsigned u; float f; } v; v.u = ((unsigned)u) << 16;
  return v.f;
}

DEV void gload_lds16(const void* g, void* l) {
  __builtin_amdgcn_global_load_lds((const __attribute__((address_space(1))) void*)g,
                                   (__attribute__((address_space(3))) void*)l, 16, 0, 0);
}

// stage(t) landed (8 newest loads may stay in flight), then meet.
DEV void vm8_bar() {
  asm volatile("s_waitcnt vmcnt(8)" ::: "memory");
  __builtin_amdgcn_s_barrier();
}
DEV void vm0_bar() {
  asm volatile("s_waitcnt vmcnt(0)" ::: "memory");
  __builtin_amdgcn_s_barrier();
}
// frag-reads retired before next iteration's DMA overwrites the buffer.
DEV void lgkm_bar() {
  asm volatile("s_waitcnt lgkmcnt(0)" ::: "memory");
  __builtin_amdgcn_s_barrier();
}

// ---------------------------------------------------------------------------
// Swizzled 128x64 bf16 tile staging (BK=64). Linear LDS dest (gid*16B);
// global source granule XOR'd by row&7. 4 granules/thread per tile.
// ---------------------------------------------------------------------------
DEV void sstage64(unsigned short* AsB, unsigned short* BsB,
                  const unsigned short* __restrict__ Arow,
                  const unsigned short* __restrict__ Brow,
                  int strideA, int strideB, int kk, int tid) {
#pragma unroll
  for (int g = 0; g < 4; ++g) {
    const int gid = g * 256 + tid;
    const int r = gid >> 3;
    const int cs = (((gid & 7) ^ (r & 7)) << 3);
    gload_lds16(Arow + (size_t)r * strideA + kk + cs, AsB + gid * 8);
    gload_lds16(Brow + (size_t)r * strideB + kk + cs, BsB + gid * 8);
  }
}

// swizzled fragment read from a [128][64] tile: global granule G = h*4+q.
DEV void fragread(bf16x8_t (&af)[4], bf16x8_t (&bff)[4],
                  const unsigned short* __restrict__ Ab,
                  const unsigned short* __restrict__ Bb,
                  int wr, int wc, int h, int q, int ln) {
  const int G = (h << 2) + q;
#pragma unroll
  for (int x = 0; x < 4; ++x) {
    const int ra = wr * 64 + x * 16 + ln;
    const int rb = wc * 64 + x * 16 + ln;
    af[x]  = *(const bf16x8_t*)(Ab + ra * 64 + ((G ^ (ra & 7)) << 3));
    bff[x] = *(const bf16x8_t*)(Bb + rb * 64 + ((G ^ (rb & 7)) << 3));
  }
}

// -------------------------- zero helpers -----------------------------------
__global__ void zero_k(unsigned short* p) { p[threadIdx.x] = 0; }

__global__ __launch_bounds__(256) void zero_rows_k(float* p) {
  int i = (blockIdx.x * 256 + threadIdx.x) * 4;
  *(float4*)(p + i) = make_float4(0.f, 0.f, 0.f, 0.f);
}

// -------------------------- f32 -> bf16 copy -------------------------------
__global__ __launch_bounds__(256) void cvt_bf16_k(const float* __restrict__ src,
                                                  unsigned short* __restrict__ dst,
                                                  int n) {
  int i = (blockIdx.x * 256 + threadIdx.x) * 4;
  if (i >= n) return;
  float4 v = *(const float4*)(src + i);
  ushort4 o;
  o.x = f2bf(v.x); o.y = f2bf(v.y); o.z = f2bf(v.z); o.w = f2bf(v.w);
  *(ushort4*)(dst + i) = o;
}

// ------------------- V: f32 [b][s][d] -> bf16 [b][d][s] --------------------
__global__ __launch_bounds__(256) void cvt_transpose_v_k(const float* __restrict__ src,
                                                         unsigned short* __restrict__ dst) {
  __shared__ float tile[32][33];
  int b = blockIdx.z, s0 = blockIdx.x * 32, d0 = blockIdx.y * 32;
  int tx = threadIdx.x & 31, ty = threadIdx.x >> 5;
  const float* p = src + ((size_t)b * 1024 + s0) * 512 + d0;
  for (int r = ty; r < 32; r += 8) tile[r][tx] = p[(size_t)r * 512 + tx];
  __syncthreads();
  unsigned short* q = dst + ((size_t)b * 512 + d0) * 1024 + s0;
  for (int r = ty; r < 32; r += 8) q[(size_t)r * 1024 + tx] = f2bf(tile[tx][r]);
}

// ------ X[b][t][c] = bf16( emb[target[t,b]] @ affine_w^T + affine_b ) ------
__global__ __launch_bounds__(256) void embed_affine_k(const int* __restrict__ tgt,
                                                      const float* __restrict__ emb,
                                                      const unsigned short* __restrict__ awb,
                                                      const float* __restrict__ ab,
                                                      unsigned short* __restrict__ X) {
  constexpr int AP = 264;
  __shared__ unsigned short xs[32 * AP];
  const int r0 = blockIdx.x * 32;
  const int tid = threadIdx.x;
  for (int idx = tid; idx < 32 * 64; idx += 256) {
    int r = idx >> 6, c4 = (idx & 63) * 4;
    int row = tgt[r0 + r];
    float4 v = *(const float4*)&emb[(size_t)row * 256 + c4];
    ushort4 o;
    o.x = f2bf(v.x); o.y = f2bf(v.y); o.z = f2bf(v.z); o.w = f2bf(v.w);
    *(ushort4*)&xs[r * AP + c4] = o;
  }
  __syncthreads();
  const int lane = tid & 63, w = tid >> 6, q = lane >> 4, ln = lane & 15;
  f32x4_t acc[2][8];
#pragma unroll
  for (int mt = 0; mt < 2; ++mt)
#pragma unroll
    for (int nt = 0; nt < 8; ++nt) acc[mt][nt] = (f32x4_t){0.f, 0.f, 0.f, 0.f};
  for (int kk = 0; kk < 256; kk += 32) {
    bf16x8_t a[2], bb[8];
#pragma unroll
    for (int mt = 0; mt < 2; ++mt)
      a[mt] = *(const bf16x8_t*)(xs + (mt * 16 + ln) * AP + kk + q * 8);
#pragma unroll
    for (int nt = 0; nt < 8; ++nt) {
      int n = ((w * 8 + nt) << 4) + ln;
      bb[nt] = *(const bf16x8_t*)(awb + ((size_t)n << 8) + kk + q * 8);
    }
#pragma unroll
    for (int mt = 0; mt < 2; ++mt)
#pragma unroll
      for (int nt = 0; nt < 8; ++nt)
        acc[mt][nt] = __builtin_amdgcn_mfma_f32_16x16x32_bf16(a[mt], bb[nt], acc[mt][nt], 0, 0, 0);
  }
#pragma unroll
  for (int nt = 0; nt < 8; ++nt) {
    const int o = ((w * 8 + nt) << 4) + ln;
    const float bias = ab[o];
#pragma unroll
    for (int mt = 0; mt < 2; ++mt)
#pragma unroll
      for (int r = 0; r < 4; ++r) {
        int rid = r0 + mt * 16 + q * 4 + r;
        int t = rid >> 5, b = rid & 31;
        X[(((size_t)(b * 1024 + t)) << 9) + o] = f2bf(acc[mt][nt][r] + bias);
      }
  }
}

// ---------------------------------------------------------------------------
// conv as tiled GEMM: C[128 l][128 o] per block, K=1536, BK=64.
// A[l][k=i*512+c] = X[b][l-2+i][c]; i = t>>3 constant within a BK64 slice.
// Causal boundary via per-lane zero-scratch redirect.
// Grid remap: all 4 n-tiles of an m-tile land on the same XCD.
// ---------------------------------------------------------------------------
DEV void cstage64(unsigned short* AsB, unsigned short* BsB,
                  const unsigned short* __restrict__ X,
                  const unsigned short* __restrict__ Wc,
                  const unsigned short* __restrict__ zbuf,
                  int b, int l0, int n0, int t, int tid) {
  const int i = t >> 3, c0 = (t & 7) << 6;
#pragma unroll
  for (int g = 0; g < 4; ++g) {
    const int gid = g * 256 + tid;
    const int r = gid >> 3;
    const int cs = (((gid & 7) ^ (r & 7)) << 3);
    const int lr = l0 + r + i - 2;
    const unsigned short* sp = (lr < 0)
        ? (zbuf + cs)
        : (X + (((size_t)(b * 1024 + lr)) << 9) + c0 + cs);
    gload_lds16(sp, AsB + gid * 8);
    gload_lds16(Wc + (size_t)(n0 + r) * 1536 + (t << 6) + cs, BsB + gid * 8);
  }
}

__global__ __launch_bounds__(256) void conv_gemm_k(const unsigned short* __restrict__ X,
                                                   const unsigned short* __restrict__ Wc,
                                                   const float* __restrict__ cb,
                                                   const unsigned short* __restrict__ zbuf,
                                                   unsigned short* __restrict__ Y) {
  __shared__ unsigned short As[2][8192];  // [128][64] bf16, x2 dbuf (16KB ea)
  __shared__ unsigned short Bs[2][8192];
  const int bid = blockIdx.x;
  // bid[2:0]=mtile_lo, bid[4:3]=ntile, bid[9:5]=mtile_hi -> bid%8 == mtile%8
  const int mtile = ((bid >> 5) << 3) | (bid & 7);   // 0..255
  const int ntile = (bid >> 3) & 3;                  // 0..3
  const int b  = mtile >> 3;
  const int l0 = (mtile & 7) << 7;
  const int n0 = ntile << 7;
  const int tid = threadIdx.x;
  const int w = tid >> 6, lane = tid & 63, q = lane >> 4, ln = lane & 15;
  const int wr = w >> 1, wc = w & 1;

  f32x4_t acc[4][4];
#pragma unroll
  for (int mt = 0; mt < 4; ++mt)
#pragma unroll
    for (int nt = 0; nt < 4; ++nt) acc[mt][nt] = (f32x4_t){0.f, 0.f, 0.f, 0.f};

  cstage64(As[0], Bs[0], X, Wc, zbuf, b, l0, n0, 0, tid);

  for (int t = 0; t < 24; ++t) {
    const int cur = t & 1;
    if (t < 23) {
      cstage64(As[cur ^ 1], Bs[cur ^ 1], X, Wc, zbuf, b, l0, n0, t + 1, tid);
      vm8_bar();   // stage(t) landed; stage(t+1)'s 8 loads stay in flight
    } else {
      vm0_bar();
    }
#pragma unroll
    for (int h = 0; h < 2; ++h) {
      bf16x8_t af[4], bff[4];
      fragread(af, bff, As[cur], Bs[cur], wr, wc, h, q, ln);
#pragma unroll
      for (int mt = 0; mt < 4; ++mt)
#pragma unroll
        for (int nt = 0; nt < 4; ++nt)
          acc[mt][nt] = __builtin_amdgcn_mfma_f32_16x16x32_bf16(af[mt], bff[nt], acc[mt][nt], 0, 0, 0);
    }
    lgkm_bar();  // reads retired before next iter's DMA overwrites this buf
  }

#pragma unroll
  for (int nt = 0; nt < 4; ++nt) {
    const int o = n0 + wc * 64 + nt * 16 + ln;
    const float bias = cb[o];
#pragma unroll
    for (int mt = 0; mt < 4; ++mt)
#pragma unroll
      for (int r = 0; r < 4; ++r) {
        const int l = l0 + wr * 64 + mt * 16 + q * 4 + r;
        float v = acc[mt][nt][r] + bias;
        Y[(((size_t)b * 1024 + l) << 9) + o] = f2bf(v > 0.f ? v : 0.f);
      }
  }
}

// ---- GLU: dec[b][l][h] = A[h] * softmax_h(Bg)[h], one wave per (b,l) row ---
__global__ __launch_bounds__(256) void glu_k(const unsigned short* __restrict__ Y,
                                             unsigned short* __restrict__ dec) {
  const int row = blockIdx.x * 4 + (threadIdx.x >> 6);
  const int lane = threadIdx.x & 63;
  const unsigned short* p = Y + ((size_t)row << 9);
  ushort4 av = *(const ushort4*)(p + lane * 4);
  ushort4 gv = *(const ushort4*)(p + 256 + lane * 4);
  float e0 = __expf(bf2f(gv.x)), e1 = __expf(bf2f(gv.y));
  float e2 = __expf(bf2f(gv.z)), e3 = __expf(bf2f(gv.w));
  float s = e0 + e1 + e2 + e3;
#pragma unroll
  for (int off = 32; off > 0; off >>= 1) s += __shfl_xor(s, off);
  float inv = 1.f / s;
  ushort4 o;
  o.x = f2bf(bf2f(av.x) * e0 * inv);
  o.y = f2bf(bf2f(av.y) * e1 * inv);
  o.z = f2bf(bf2f(av.z) * e2 * inv);
  o.w = f2bf(bf2f(av.w) * e3 * inv);
  *(ushort4*)(dec + ((size_t)row << 8) + lane * 4) = o;
}

// ---------------------------------------------------------------------------
// attn GEMM1: P[row][s] = exp( dec[row] . enc_b[s] ), rowsum atomics.
// M=32768, N=1024, K=256 (4 BK64 steps). Grid 2048, XCD-contiguous swizzle.
// ---------------------------------------------------------------------------
__global__ __launch_bounds__(256) void attn_s_k(const unsigned short* __restrict__ dec,
                                                const unsigned short* __restrict__ enc,
                                                unsigned short* __restrict__ P,
                                                float* __restrict__ rows) {
  __shared__ unsigned short As[2][8192];
  __shared__ unsigned short Bs[2][8192];
  const int bid = blockIdx.x;
  const int wg = ((bid & 7) << 8) + (bid >> 3);  // bijective: 2048 % 8 == 0
  const int ntile = wg & 7, mtile = wg >> 3;
  const int b = mtile >> 3;
  const int row0 = mtile << 7;
  const int s0 = ntile << 7;
  const int tid = threadIdx.x;
  const int w = tid >> 6, lane = tid & 63, q = lane >> 4, ln = lane & 15;
  const int wr = w >> 1, wc = w & 1;

  const unsigned short* Ab = dec + ((size_t)row0 << 8);                    // [128][256]
  const unsigned short* Bb = enc + ((size_t)b << 18) + ((size_t)s0 << 8);  // [128][256]

  f32x4_t acc[4][4];
#pragma unroll
  for (int mt = 0; mt < 4; ++mt)
#pragma unroll
    for (int nt = 0; nt < 4; ++nt) acc[mt][nt] = (f32x4_t){0.f, 0.f, 0.f, 0.f};

  sstage64(As[0], Bs[0], Ab, Bb, 256, 256, 0, tid);

  for (int t = 0; t < 4; ++t) {
    const int cur = t & 1;
    if (t < 3) {
      sstage64(As[cur ^ 1], Bs[cur ^ 1], Ab, Bb, 256, 256, (t + 1) << 6, tid);
      vm8_bar();
    } else {
      vm0_bar();
    }
#pragma unroll
    for (int h = 0; h < 2; ++h) {
      bf16x8_t af[4], bff[4];
      fragread(af, bff, As[cur], Bs[cur], wr, wc, h, q, ln);
#pragma unroll
      for (int mt = 0; mt < 4; ++mt)
#pragma unroll
        for (int nt = 0; nt < 4; ++nt)
          acc[mt][nt] = __builtin_amdgcn_mfma_f32_16x16x32_bf16(af[mt], bff[nt], acc[mt][nt], 0, 0, 0);
    }
    lgkm_bar();
  }

  // epilogue: exp -> bf16 P store; f32 rowsum partials -> wave reduce -> atomic
  float rs[4][4];
#pragma unroll
  for (int mt = 0; mt < 4; ++mt)
#pragma unroll
    for (int r = 0; r < 4; ++r) rs[mt][r] = 0.f;
#pragma unroll
  for (int nt = 0; nt < 4; ++nt) {
    const int col = s0 + wc * 64 + nt * 16 + ln;
#pragma unroll
    for (int mt = 0; mt < 4; ++mt)
#pragma unroll
      for (int r = 0; r < 4; ++r) {
        const int row = row0 + wr * 64 + mt * 16 + q * 4 + r;
        float e = __expf(acc[mt][nt][r]);
        rs[mt][r] += e;
        P[((size_t)row << 10) + col] = f2bf(e);
      }
  }
#pragma unroll
  for (int mt = 0; mt < 4; ++mt)
#pragma unroll
    for (int r = 0; r < 4; ++r) {
      float v = rs[mt][r];
      v += __shfl_xor(v, 1); v += __shfl_xor(v, 2);
      v += __shfl_xor(v, 4); v += __shfl_xor(v, 8);
      if (ln == 0)
        atomicAdd(&rows[row0 + wr * 64 + mt * 16 + q * 4 + r], v);
    }
}

// ---------------------------------------------------------------------------
// attn GEMM2: out[row][d] = (P[row] . V^T[d]) * rinv[row] + dec[row] . mw[d]
//             + mb[d]. M=32768, N=512, K=1024 (16 steps) + 256 (4 map steps).
// rinv applied between t==15 MFMA and t==16. Grid 1024, XCD swizzle.
// ---------------------------------------------------------------------------
__global__ __launch_bounds__(256) void attn_pv_k(const unsigned short* __restrict__ P,
                                                 const unsigned short* __restrict__ vt,
                                                 const unsigned short* __restrict__ dec,
                                                 const unsigned short* __restrict__ mw,
                                                 const float* __restrict__ rows,
                                                 const float* __restrict__ mb,
                                                 float* __restrict__ out) {
  __shared__ unsigned short As[2][8192];
  __shared__ unsigned short Bs[2][8192];
  const int bid = blockIdx.x;
  const int wg = ((bid & 7) << 7) + (bid >> 3);  // bijective: 1024 % 8 == 0
  const int ntile = wg & 3, mtile = wg >> 2;
  const int b = mtile >> 3;
  const int row0 = mtile << 7;
  const int d0 = ntile << 7;
  const int tid = threadIdx.x;
  const int w = tid >> 6, lane = tid & 63, q = lane >> 4, ln = lane & 15;
  const int wr = w >> 1, wc = w & 1;

  const unsigned short* A1 = P + ((size_t)row0 << 10);                    // [128][1024]
  const unsigned short* B1 = vt + ((size_t)b << 19) + ((size_t)d0 << 10); // [128][1024]
  const unsigned short* A2 = dec + ((size_t)row0 << 8);                   // [128][256]
  const unsigned short* B2 = mw + ((size_t)d0 << 8);                      // [128][256]

  // rinv (rowsums are final: previous kernel finished)
  float rinv[4][4];
#pragma unroll
  for (int mt = 0; mt < 4; ++mt)
#pragma unroll
    for (int r = 0; r < 4; ++r)
      rinv[mt][r] = 1.f / rows[row0 + wr * 64 + mt * 16 + q * 4 + r];

  f32x4_t acc[4][4];
#pragma unroll
  for (int mt = 0; mt < 4; ++mt)
#pragma unroll
    for (int nt = 0; nt < 4; ++nt) acc[mt][nt] = (f32x4_t){0.f, 0.f, 0.f, 0.f};

  sstage64(As[0], Bs[0], A1, B1, 1024, 1024, 0, tid);

  for (int t = 0; t < 20; ++t) {
    const int cur = t & 1;
    if (t < 19) {
      const int tn = t + 1;
      if (tn < 16)
        sstage64(As[cur ^ 1], Bs[cur ^ 1], A1, B1, 1024, 1024, tn << 6, tid);
      else
        sstage64(As[cur ^ 1], Bs[cur ^ 1], A2, B2, 256, 256, (tn - 16) << 6, tid);
      vm8_bar();
    } else {
      vm0_bar();
    }
#pragma unroll
    for (int h = 0; h < 2; ++h) {
      bf16x8_t af[4], bff[4];
      fragread(af, bff, As[cur], Bs[cur], wr, wc, h, q, ln);
#pragma unroll
      for (int mt = 0; mt < 4; ++mt)
#pragma unroll
        for (int nt = 0; nt < 4; ++nt)
          acc[mt][nt] = __builtin_amdgcn_mfma_f32_16x16x32_bf16(af[mt], bff[nt], acc[mt][nt], 0, 0, 0);
    }
    if (t == 15) {
      // PV phase done: normalize by rowsum before map chunk accumulates
#pragma unroll
      for (int mt = 0; mt < 4; ++mt)
#pragma unroll
        for (int nt = 0; nt < 4; ++nt)
#pragma unroll
          for (int r = 0; r < 4; ++r) acc[mt][nt][r] *= rinv[mt][r];
    }
    lgkm_bar();
  }

  // epilogue: + bias, store f32, skip l == 1023
#pragma unroll
  for (int nt = 0; nt < 4; ++nt) {
    const int d = d0 + wc * 64 + nt * 16 + ln;
    const float bias = mb[d];
#pragma unroll
    for (int mt = 0; mt < 4; ++mt)
#pragma unroll
      for (int r = 0; r < 4; ++r) {
        const int row = row0 + wr * 64 + mt * 16 + q * 4 + r;
        const int l = row & 1023;
        if (l < 1023)
          out[((size_t)b * 1023 + l) * 512 + d] = acc[mt][nt][r] + bias;
      }
  }
}

// ---------------------------------------------------------------------------
extern "C" void kernel_launch(void* const* d_in, const int* in_sizes, int n_in,
                              void* d_out, int out_size, void* d_ws, size_t ws_size,
                              hipStream_t stream) {
  const int*   target = (const int*)d_in[1];
  const float* enc    = (const float*)d_in[2];
  const float* src    = (const float*)d_in[3];
  const float* emb    = (const float*)d_in[4];
  const float* aw     = (const float*)d_in[5];
  const float* ab     = (const float*)d_in[6];
  const float* cw     = (const float*)d_in[7];
  const float* cb     = (const float*)d_in[8];
  const float* mw     = (const float*)d_in[9];
  const float* mb     = (const float*)d_in[10];
  float* out = (float*)d_out;
  char* ws = (char*)d_ws;

  unsigned short* Xbf  = (unsigned short*)(ws);            // P aliases Xbf+Ybf
  unsigned short* Ybf  = (unsigned short*)(ws + 33554432);
  unsigned short* Pb   = (unsigned short*)(ws);            // [32768][1024] bf16
  unsigned short* dec  = (unsigned short*)(ws + 67108864);
  unsigned short* encb = (unsigned short*)(ws + 83886080);
  unsigned short* vtb  = (unsigned short*)(ws + 100663296);
  unsigned short* wcb  = (unsigned short*)(ws + 134217728);
  float*          rows = (float*)(ws + 134217728);         // reuses wcb post-conv
  unsigned short* mwb  = (unsigned short*)(ws + 135790592);
  unsigned short* awb  = (unsigned short*)(ws + 136052736);

  zero_k<<<1, 512, 0, stream>>>(dec);  // 1KB zero scratch for conv boundary
  cvt_bf16_k<<<8192, 256, 0, stream>>>(enc, encb, 32 * 1024 * 256);
  cvt_bf16_k<<<768, 256, 0, stream>>>(cw, wcb, 512 * 1536);
  cvt_bf16_k<<<128, 256, 0, stream>>>(mw, mwb, 512 * 256);
  cvt_bf16_k<<<128, 256, 0, stream>>>(aw, awb, 512 * 256);
  cvt_transpose_v_k<<<dim3(32, 16, 32), 256, 0, stream>>>(src, vtb);
  embed_affine_k<<<1024, 256, 0, stream>>>(target, emb, awb, ab, Xbf);
  conv_gemm_k<<<1024, 256, 0, stream>>>(Xbf, wcb, cb, dec, Ybf);
  zero_rows_k<<<32, 256, 0, stream>>>(rows);   // wcb dead after conv
  glu_k<<<8192, 256, 0, stream>>>(Ybf, dec);
  attn_s_k<<<2048, 256, 0, stream>>>(dec, encb, Pb, rows);
  attn_pv_k<<<1024, 256, 0, stream>>>(Pb, vtb, dec, mwb, rows, mb, out);
}

// Round 6
// 415.638 us; speedup vs baseline: 1.5639x; 1.0600x over previous
//
#include <hip/hip_runtime.h>
#include <stdint.h>

// ---------------------------------------------------------------------------
// Decoder block: emb-gather+affine -> causal conv(K=3) -> relu -> GLU(softmax)
//                -> map matmul (+) cross-attention (QK^T softmax PV)
// Shapes: V=50257 E=256 H=256 2H=512 K=3 T=1024 B=32 S=1024 L=1023
// Output: (32, 1023, 512) f32
// R9: GEMM kernels moved to a 3-stage BK32 pipeline:
//   - 3 LDS buffers x 16KB = 48KB -> 3 blocks/CU (R8's 64KB gave only 2)
//   - prefetch distance 2 tiles; counted vmcnt(8) (2 stages always in flight,
//     never a drain); lgkmcnt(0)+barrier protects buffer reuse
//   - staging addresses strength-reduced: per-thread granule base + t*64B
//     (conv A is linear in k: addr=(l-2)*512+k; boundary via per-thread tmin)
//   - BK32 granule swizzle (g ^= r&3): residual 4-way on ds_read accepted
// cvt_transpose_v rewritten: 64x64 tile, float4 loads, ushort8 stores
// (128B contiguous per output row vs old 2B scalar stores).
// Workspace layout (bytes):
//   Xbf   [32][1024][512] bf16 @ 0          (33,554,432)  \ P [32768][1024]
//   Ybf   [32][1024][512] bf16 @ 33554432   (33,554,432)  / bf16 after glu
//   dec   [32][1024][256] bf16 @ 67108864   (16,777,216)  (first 1KB = zero
//                                            scratch for conv boundary)
//   encb  [32][1024][256] bf16 @ 83886080   (16,777,216)
//   vtb   [32][512][1024] bf16 @ 100663296  (33,554,432)  (V transposed)
//   wcb   [512][1536]     bf16 @ 134217728  ( 1,572,864)  (first 128KB reused
//                                            as f32 rowsums after conv)
//   mwb   [512][256]      bf16 @ 135790592  (   262,144)
//   awb   [512][256]      bf16 @ 136052736  (   262,144)
// ---------------------------------------------------------------------------

typedef __bf16 bf16x8_t __attribute__((ext_vector_type(8)));
typedef float  f32x4_t  __attribute__((ext_vector_type(4)));
typedef unsigned short u16x8 __attribute__((ext_vector_type(8)));

#define DEV __device__ __forceinline__

DEV unsigned short f2bf(float f) {
  union { float f; unsigned u; } v; v.f = f;
  unsigned r = v.u + 0x7fffu + ((v.u >> 16) & 1u);
  return (unsigned short)(r >> 16);
}
DEV float bf2f(unsigned short u) {
  union { unsigned u; float f; } v; v.u = ((unsigned)u) << 16;
  return v.f;
}

DEV void gload_lds16(const void* g, void* l) {
  __builtin_amdgcn_global_load_lds((const __attribute__((address_space(1))) void*)g,
                                   (__attribute__((address_space(3))) void*)l, 16, 0, 0);
}

DEV void vm_bar8() { asm volatile("s_waitcnt vmcnt(8)" ::: "memory"); __builtin_amdgcn_s_barrier(); }
DEV void vm_bar4() { asm volatile("s_waitcnt vmcnt(4)" ::: "memory"); __builtin_amdgcn_s_barrier(); }
DEV void vm_bar0() { asm volatile("s_waitcnt vmcnt(0)" ::: "memory"); __builtin_amdgcn_s_barrier(); }
DEV void lgkm_bar() { asm volatile("s_waitcnt lgkmcnt(0)" ::: "memory"); __builtin_amdgcn_s_barrier(); }

// ---------------------------------------------------------------------------
// 3-stage BK32 pipeline pieces. LDS buffer layout per stage (8192 ushorts):
//   A tile [128 rows][32 k] at [0..4095], B tile at [4096..8191].
//   Granule gid (0..511 per operand): row r = gid>>2, lds-granule g = gid&3,
//   holding SOURCE column-granule g ^ (r&3)  (bijective swizzle).
// Each thread stages gid = tid and tid+256 for A and B -> 4 loads/tile.
// ---------------------------------------------------------------------------
DEV void stage32(unsigned short* Ld, int tid,
                 const unsigned short* a0, const unsigned short* a1,
                 const unsigned short* b0, const unsigned short* b1, int tt) {
  const int o = tt * 32;
  gload_lds16(a0 + o, Ld + tid * 8);
  gload_lds16(a1 + o, Ld + (tid + 256) * 8);
  gload_lds16(b0 + o, Ld + 4096 + tid * 8);
  gload_lds16(b1 + o, Ld + 4096 + (tid + 256) * 8);
}

// one BK32 step: 8 swizzled ds_read_b128 + 16 MFMA (setprio-wrapped)
DEV void gemm_step32(const unsigned short* Ld, int wr, int wc, int ln, int qsw,
                     f32x4_t (&acc)[4][4]) {
  bf16x8_t af[4], bff[4];
#pragma unroll
  for (int x = 0; x < 4; ++x) {
    af[x]  = *(const bf16x8_t*)(Ld + (wr * 64 + x * 16 + ln) * 32 + qsw);
    bff[x] = *(const bf16x8_t*)(Ld + 4096 + (wc * 64 + x * 16 + ln) * 32 + qsw);
  }
  __builtin_amdgcn_s_setprio(1);
#pragma unroll
  for (int mt = 0; mt < 4; ++mt)
#pragma unroll
    for (int nt = 0; nt < 4; ++nt)
      acc[mt][nt] = __builtin_amdgcn_mfma_f32_16x16x32_bf16(af[mt], bff[nt], acc[mt][nt], 0, 0, 0);
  __builtin_amdgcn_s_setprio(0);
}

// -------------------------- zero helpers -----------------------------------
__global__ void zero_k(unsigned short* p) { p[threadIdx.x] = 0; }

__global__ __launch_bounds__(256) void zero_rows_k(float* p) {
  int i = (blockIdx.x * 256 + threadIdx.x) * 4;
  *(float4*)(p + i) = make_float4(0.f, 0.f, 0.f, 0.f);
}

// -------------------------- f32 -> bf16 copy -------------------------------
__global__ __launch_bounds__(256) void cvt_bf16_k(const float* __restrict__ src,
                                                  unsigned short* __restrict__ dst,
                                                  int n) {
  int i = (blockIdx.x * 256 + threadIdx.x) * 4;
  if (i >= n) return;
  float4 v = *(const float4*)(src + i);
  ushort4 o;
  o.x = f2bf(v.x); o.y = f2bf(v.y); o.z = f2bf(v.z); o.w = f2bf(v.w);
  *(ushort4*)(dst + i) = o;
}

// ------------------- V: f32 [b][s][d] -> bf16 [b][d][s] --------------------
// 64x64 tile; float4 coalesced loads, ushort8 stores (128B/row contiguous).
__global__ __launch_bounds__(256) void cvt_transpose_v_k(const float* __restrict__ src,
                                                         unsigned short* __restrict__ dst) {
  __shared__ float tile[64][65];
  const int b = blockIdx.z, s0 = blockIdx.x * 64, d0 = blockIdx.y * 64;
  const int tid = threadIdx.x;
  const int cs = (tid & 15) * 4;   // d within tile
  const int rs = tid >> 4;         // s within tile (16/pass)
  const float* p = src + ((size_t)b * 1024 + s0) * 512 + d0;
#pragma unroll
  for (int rr = 0; rr < 4; ++rr) {
    const int s = rs + rr * 16;
    float4 v = *(const float4*)(p + (size_t)s * 512 + cs);
    tile[s][cs] = v.x; tile[s][cs + 1] = v.y;
    tile[s][cs + 2] = v.z; tile[s][cs + 3] = v.w;
  }
  __syncthreads();
  const int ch = tid & 7;          // 8 s-chunks of 8
  const int dd0 = tid >> 3;        // 32 d rows per pass
#pragma unroll
  for (int it = 0; it < 2; ++it) {
    const int dd = dd0 + it * 32;
    u16x8 o;
#pragma unroll
    for (int j = 0; j < 8; ++j) o[j] = f2bf(tile[ch * 8 + j][dd]);
    *(u16x8*)(dst + ((size_t)b * 512 + d0 + dd) * 1024 + s0 + ch * 8) = o;
  }
}

// ------ X[b][t][c] = bf16( emb[target[t,b]] @ affine_w^T + affine_b ) ------
__global__ __launch_bounds__(256) void embed_affine_k(const int* __restrict__ tgt,
                                                      const float* __restrict__ emb,
                                                      const unsigned short* __restrict__ awb,
                                                      const float* __restrict__ ab,
                                                      unsigned short* __restrict__ X) {
  constexpr int AP = 264;
  __shared__ unsigned short xs[32 * AP];
  const int r0 = blockIdx.x * 32;
  const int tid = threadIdx.x;
  for (int idx = tid; idx < 32 * 64; idx += 256) {
    int r = idx >> 6, c4 = (idx & 63) * 4;
    int row = tgt[r0 + r];
    float4 v = *(const float4*)&emb[(size_t)row * 256 + c4];
    ushort4 o;
    o.x = f2bf(v.x); o.y = f2bf(v.y); o.z = f2bf(v.z); o.w = f2bf(v.w);
    *(ushort4*)&xs[r * AP + c4] = o;
  }
  __syncthreads();
  const int lane = tid & 63, w = tid >> 6, q = lane >> 4, ln = lane & 15;
  f32x4_t acc[2][8];
#pragma unroll
  for (int mt = 0; mt < 2; ++mt)
#pragma unroll
    for (int nt = 0; nt < 8; ++nt) acc[mt][nt] = (f32x4_t){0.f, 0.f, 0.f, 0.f};
  for (int kk = 0; kk < 256; kk += 32) {
    bf16x8_t a[2], bb[8];
#pragma unroll
    for (int mt = 0; mt < 2; ++mt)
      a[mt] = *(const bf16x8_t*)(xs + (mt * 16 + ln) * AP + kk + q * 8);
#pragma unroll
    for (int nt = 0; nt < 8; ++nt) {
      int n = ((w * 8 + nt) << 4) + ln;
      bb[nt] = *(const bf16x8_t*)(awb + ((size_t)n << 8) + kk + q * 8);
    }
#pragma unroll
    for (int mt = 0; mt < 2; ++mt)
#pragma unroll
      for (int nt = 0; nt < 8; ++nt)
        acc[mt][nt] = __builtin_amdgcn_mfma_f32_16x16x32_bf16(a[mt], bb[nt], acc[mt][nt], 0, 0, 0);
  }
#pragma unroll
  for (int nt = 0; nt < 8; ++nt) {
    const int o = ((w * 8 + nt) << 4) + ln;
    const float bias = ab[o];
#pragma unroll
    for (int mt = 0; mt < 2; ++mt)
#pragma unroll
      for (int r = 0; r < 4; ++r) {
        int rid = r0 + mt * 16 + q * 4 + r;
        int t = rid >> 5, b = rid & 31;
        X[(((size_t)(b * 1024 + t)) << 9) + o] = f2bf(acc[mt][nt][r] + bias);
      }
  }
}

// ---------------------------------------------------------------------------
// conv as tiled GEMM: C[128 l][128 o], K=1536, BK=32, 3-stage pipeline.
// A element addr = (l0+r-2)*512 + k  (linear in k). Boundary rows (only
// l0==0, r<2) redirect to zbuf while t < tmin (r==0: t<32, r==1: t<16).
// ---------------------------------------------------------------------------
__global__ __launch_bounds__(256, 3) void conv_gemm_k(const unsigned short* __restrict__ X,
                                                      const unsigned short* __restrict__ Wc,
                                                      const float* __restrict__ cb,
                                                      const unsigned short* __restrict__ zbuf,
                                                      unsigned short* __restrict__ Y) {
  __shared__ unsigned short tb[3][8192];
  const int bid = blockIdx.x;
  // bid%8 == mtile%8 -> all 4 n-tiles of an m-tile on one XCD
  const int mtile = ((bid >> 5) << 3) | (bid & 7);
  const int ntile = (bid >> 3) & 3;
  const int b  = mtile >> 3;
  const int l0 = (mtile & 7) << 7;
  const int n0 = ntile << 7;
  const int tid = threadIdx.x;
  const int w = tid >> 6, lane = tid & 63, q = lane >> 4, ln = lane & 15;
  const int wr = w >> 1, wc = w & 1;
  const int qsw = (q ^ (ln & 3)) << 3;

  const int r0g = tid >> 2, r1g = (tid + 256) >> 2;
  const int cg = tid & 3;
  const int c0g = ((cg ^ (r0g & 3)) << 3);
  const int c1g = ((cg ^ (r1g & 3)) << 3);

  const unsigned short* Xb = X + ((size_t)b << 19);
  const int lr0 = l0 + r0g - 2;               // can be -2..-1 (l0==0 only)
  const int lr1 = l0 + r1g - 2;               // >= 62, never negative
  const int tmin0 = (lr0 >= 0) ? 0 : (lr0 == -1 ? 16 : 32);
  const unsigned short* a0 = Xb + ((long)lr0 * 512 + c0g);
  const unsigned short* a1 = Xb + ((long)lr1 * 512 + c1g);
  const unsigned short* b0 = Wc + (size_t)(n0 + r0g) * 1536 + c0g;
  const unsigned short* b1 = Wc + (size_t)(n0 + r1g) * 1536 + c1g;

  auto STG = [&](unsigned short* Ld, int tt) {
    const int o = tt * 32;
    const unsigned short* sA0 = (tt >= tmin0) ? (a0 + o) : (zbuf + c0g);
    gload_lds16(sA0, Ld + tid * 8);
    gload_lds16(a1 + o, Ld + (tid + 256) * 8);
    gload_lds16(b0 + o, Ld + 4096 + tid * 8);
    gload_lds16(b1 + o, Ld + 4096 + (tid + 256) * 8);
  };

  f32x4_t acc[4][4];
#pragma unroll
  for (int mt = 0; mt < 4; ++mt)
#pragma unroll
    for (int nt = 0; nt < 4; ++nt) acc[mt][nt] = (f32x4_t){0.f, 0.f, 0.f, 0.f};

  unsigned short *p0 = tb[0], *p1 = tb[1], *p2 = tb[2];
  STG(p0, 0);
  STG(p1, 1);

  for (int t = 0; t < 48; ++t) {
    if (t + 2 < 48) { STG(p2, t + 2); vm_bar8(); }
    else if (t + 1 < 48) vm_bar4();
    else vm_bar0();
    gemm_step32(p0, wr, wc, ln, qsw, acc);
    lgkm_bar();
    unsigned short* tmp = p0; p0 = p1; p1 = p2; p2 = tmp;
  }

#pragma unroll
  for (int nt = 0; nt < 4; ++nt) {
    const int o = n0 + wc * 64 + nt * 16 + ln;
    const float bias = cb[o];
#pragma unroll
    for (int mt = 0; mt < 4; ++mt)
#pragma unroll
      for (int r = 0; r < 4; ++r) {
        const int l = l0 + wr * 64 + mt * 16 + q * 4 + r;
        float v = acc[mt][nt][r] + bias;
        Y[(((size_t)b * 1024 + l) << 9) + o] = f2bf(v > 0.f ? v : 0.f);
      }
  }
}

// ---- GLU: dec[b][l][h] = A[h] * softmax_h(Bg)[h], one wave per (b,l) row ---
__global__ __launch_bounds__(256) void glu_k(const unsigned short* __restrict__ Y,
                                             unsigned short* __restrict__ dec) {
  const int row = blockIdx.x * 4 + (threadIdx.x >> 6);
  const int lane = threadIdx.x & 63;
  const unsigned short* p = Y + ((size_t)row << 9);
  ushort4 av = *(const ushort4*)(p + lane * 4);
  ushort4 gv = *(const ushort4*)(p + 256 + lane * 4);
  float e0 = __expf(bf2f(gv.x)), e1 = __expf(bf2f(gv.y));
  float e2 = __expf(bf2f(gv.z)), e3 = __expf(bf2f(gv.w));
  float s = e0 + e1 + e2 + e3;
#pragma unroll
  for (int off = 32; off > 0; off >>= 1) s += __shfl_xor(s, off);
  float inv = 1.f / s;
  ushort4 o;
  o.x = f2bf(bf2f(av.x) * e0 * inv);
  o.y = f2bf(bf2f(av.y) * e1 * inv);
  o.z = f2bf(bf2f(av.z) * e2 * inv);
  o.w = f2bf(bf2f(av.w) * e3 * inv);
  *(ushort4*)(dec + ((size_t)row << 8) + lane * 4) = o;
}

// ---------------------------------------------------------------------------
// attn GEMM1: P[row][s] = exp( dec[row] . enc_b[s] ), rowsum atomics.
// M=32768, N=1024, K=256 (8 BK32 tiles). Grid 2048, XCD swizzle.
// ---------------------------------------------------------------------------
__global__ __launch_bounds__(256, 3) void attn_s_k(const unsigned short* __restrict__ dec,
                                                   const unsigned short* __restrict__ enc,
                                                   unsigned short* __restrict__ P,
                                                   float* __restrict__ rows) {
  __shared__ unsigned short tb[3][8192];
  const int bid = blockIdx.x;
  const int wg = ((bid & 7) << 8) + (bid >> 3);  // bijective: 2048 % 8 == 0
  const int ntile = wg & 7, mtile = wg >> 3;
  const int b = mtile >> 3;
  const int row0 = mtile << 7;
  const int s0 = ntile << 7;
  const int tid = threadIdx.x;
  const int w = tid >> 6, lane = tid & 63, q = lane >> 4, ln = lane & 15;
  const int wr = w >> 1, wc = w & 1;
  const int qsw = (q ^ (ln & 3)) << 3;

  const int r0g = tid >> 2, r1g = (tid + 256) >> 2;
  const int cg = tid & 3;
  const int c0g = ((cg ^ (r0g & 3)) << 3);
  const int c1g = ((cg ^ (r1g & 3)) << 3);

  const unsigned short* Ab = dec + ((size_t)row0 << 8);
  const unsigned short* Bb = enc + ((size_t)b << 18) + ((size_t)s0 << 8);
  const unsigned short* a0 = Ab + (size_t)r0g * 256 + c0g;
  const unsigned short* a1 = Ab + (size_t)r1g * 256 + c1g;
  const unsigned short* b0 = Bb + (size_t)r0g * 256 + c0g;
  const unsigned short* b1 = Bb + (size_t)r1g * 256 + c1g;

  f32x4_t acc[4][4];
#pragma unroll
  for (int mt = 0; mt < 4; ++mt)
#pragma unroll
    for (int nt = 0; nt < 4; ++nt) acc[mt][nt] = (f32x4_t){0.f, 0.f, 0.f, 0.f};

  unsigned short *p0 = tb[0], *p1 = tb[1], *p2 = tb[2];
  stage32(p0, tid, a0, a1, b0, b1, 0);
  stage32(p1, tid, a0, a1, b0, b1, 1);

  for (int t = 0; t < 8; ++t) {
    if (t + 2 < 8) { stage32(p2, tid, a0, a1, b0, b1, t + 2); vm_bar8(); }
    else if (t + 1 < 8) vm_bar4();
    else vm_bar0();
    gemm_step32(p0, wr, wc, ln, qsw, acc);
    lgkm_bar();
    unsigned short* tmp = p0; p0 = p1; p1 = p2; p2 = tmp;
  }

  // epilogue: exp -> bf16 P store; f32 rowsum partials -> wave reduce -> atomic
  float rs[4][4];
#pragma unroll
  for (int mt = 0; mt < 4; ++mt)
#pragma unroll
    for (int r = 0; r < 4; ++r) rs[mt][r] = 0.f;
#pragma unroll
  for (int nt = 0; nt < 4; ++nt) {
    const int col = s0 + wc * 64 + nt * 16 + ln;
#pragma unroll
    for (int mt = 0; mt < 4; ++mt)
#pragma unroll
      for (int r = 0; r < 4; ++r) {
        const int row = row0 + wr * 64 + mt * 16 + q * 4 + r;
        float e = __expf(acc[mt][nt][r]);
        rs[mt][r] += e;
        P[((size_t)row << 10) + col] = f2bf(e);
      }
  }
#pragma unroll
  for (int mt = 0; mt < 4; ++mt)
#pragma unroll
    for (int r = 0; r < 4; ++r) {
      float v = rs[mt][r];
      v += __shfl_xor(v, 1); v += __shfl_xor(v, 2);
      v += __shfl_xor(v, 4); v += __shfl_xor(v, 8);
      if (ln == 0)
        atomicAdd(&rows[row0 + wr * 64 + mt * 16 + q * 4 + r], v);
    }
}

// ---------------------------------------------------------------------------
// attn GEMM2: out[row][d] = (P[row] . V^T[d]) * rinv[row] + dec[row] . mw[d]
//             + mb[d]. K = 1024 (32 PV tiles) + 256 (8 map tiles).
// rinv applied between the two loops. Grid 1024, XCD swizzle.
// ---------------------------------------------------------------------------
__global__ __launch_bounds__(256, 3) void attn_pv_k(const unsigned short* __restrict__ P,
                                                    const unsigned short* __restrict__ vt,
                                                    const unsigned short* __restrict__ dec,
                                                    const unsigned short* __restrict__ mw,
                                                    const float* __restrict__ rows,
                                                    const float* __restrict__ mb,
                                                    float* __restrict__ out) {
  __shared__ unsigned short tb[3][8192];
  const int bid = blockIdx.x;
  const int wg = ((bid & 7) << 7) + (bid >> 3);  // bijective: 1024 % 8 == 0
  const int ntile = wg & 3, mtile = wg >> 2;
  const int b = mtile >> 3;
  const int row0 = mtile << 7;
  const int d0 = ntile << 7;
  const int tid = threadIdx.x;
  const int w = tid >> 6, lane = tid & 63, q = lane >> 4, ln = lane & 15;
  const int wr = w >> 1, wc = w & 1;
  const int qsw = (q ^ (ln & 3)) << 3;

  const int r0g = tid >> 2, r1g = (tid + 256) >> 2;
  const int cg = tid & 3;
  const int c0g = ((cg ^ (r0g & 3)) << 3);
  const int c1g = ((cg ^ (r1g & 3)) << 3);

  const unsigned short* A1 = P + ((size_t)row0 << 10);
  const unsigned short* B1 = vt + ((size_t)b << 19) + ((size_t)d0 << 10);
  const unsigned short* A2 = dec + ((size_t)row0 << 8);
  const unsigned short* B2 = mw + ((size_t)d0 << 8);
  const unsigned short* a10 = A1 + (size_t)r0g * 1024 + c0g;
  const unsigned short* a11 = A1 + (size_t)r1g * 1024 + c1g;
  const unsigned short* b10 = B1 + (size_t)r0g * 1024 + c0g;
  const unsigned short* b11 = B1 + (size_t)r1g * 1024 + c1g;
  const unsigned short* a20 = A2 + (size_t)r0g * 256 + c0g;
  const unsigned short* a21 = A2 + (size_t)r1g * 256 + c1g;
  const unsigned short* b20 = B2 + (size_t)r0g * 256 + c0g;
  const unsigned short* b21 = B2 + (size_t)r1g * 256 + c1g;

  auto STG = [&](unsigned short* Ld, int tt) {
    if (tt < 32) stage32(Ld, tid, a10, a11, b10, b11, tt);
    else         stage32(Ld, tid, a20, a21, b20, b21, tt - 32);
  };

  // rinv loads issued first: they are the oldest in the vm FIFO, so the
  // first vm_bar8 retires them together with stage(0).
  float rinv[4][4];
#pragma unroll
  for (int mt = 0; mt < 4; ++mt)
#pragma unroll
    for (int r = 0; r < 4; ++r)
      rinv[mt][r] = 1.f / rows[row0 + wr * 64 + mt * 16 + q * 4 + r];

  f32x4_t acc[4][4];
#pragma unroll
  for (int mt = 0; mt < 4; ++mt)
#pragma unroll
    for (int nt = 0; nt < 4; ++nt) acc[mt][nt] = (f32x4_t){0.f, 0.f, 0.f, 0.f};

  unsigned short *p0 = tb[0], *p1 = tb[1], *p2 = tb[2];
  STG(p0, 0);
  STG(p1, 1);

  for (int t = 0; t < 32; ++t) {          // PV phase (stage reaches t+2<=33)
    STG(p2, t + 2); vm_bar8();
    gemm_step32(p0, wr, wc, ln, qsw, acc);
    lgkm_bar();
    unsigned short* tmp = p0; p0 = p1; p1 = p2; p2 = tmp;
  }
  // PV done: normalize by rowsum before the map chunk accumulates
#pragma unroll
  for (int mt = 0; mt < 4; ++mt)
#pragma unroll
    for (int nt = 0; nt < 4; ++nt)
#pragma unroll
      for (int r = 0; r < 4; ++r) acc[mt][nt][r] *= rinv[mt][r];

  for (int t = 32; t < 40; ++t) {         // map phase
    if (t + 2 < 40) { STG(p2, t + 2); vm_bar8(); }
    else if (t + 1 < 40) vm_bar4();
    else vm_bar0();
    gemm_step32(p0, wr, wc, ln, qsw, acc);
    lgkm_bar();
    unsigned short* tmp = p0; p0 = p1; p1 = p2; p2 = tmp;
  }

  // epilogue: + bias, store f32, skip l == 1023
#pragma unroll
  for (int nt = 0; nt < 4; ++nt) {
    const int d = d0 + wc * 64 + nt * 16 + ln;
    const float bias = mb[d];
#pragma unroll
    for (int mt = 0; mt < 4; ++mt)
#pragma unroll
      for (int r = 0; r < 4; ++r) {
        const int row = row0 + wr * 64 + mt * 16 + q * 4 + r;
        const int l = row & 1023;
        if (l < 1023)
          out[((size_t)b * 1023 + l) * 512 + d] = acc[mt][nt][r] + bias;
      }
  }
}

// ---------------------------------------------------------------------------
extern "C" void kernel_launch(void* const* d_in, const int* in_sizes, int n_in,
                              void* d_out, int out_size, void* d_ws, size_t ws_size,
                              hipStream_t stream) {
  const int*   target = (const int*)d_in[1];
  const float* enc    = (const float*)d_in[2];
  const float* src    = (const float*)d_in[3];
  const float* emb    = (const float*)d_in[4];
  const float* aw     = (const float*)d_in[5];
  const float* ab     = (const float*)d_in[6];
  const float* cw     = (const float*)d_in[7];
  const float* cb     = (const float*)d_in[8];
  const float* mw     = (const float*)d_in[9];
  const float* mb     = (const float*)d_in[10];
  float* out = (float*)d_out;
  char* ws = (char*)d_ws;

  unsigned short* Xbf  = (unsigned short*)(ws);            // P aliases Xbf+Ybf
  unsigned short* Ybf  = (unsigned short*)(ws + 33554432);
  unsigned short* Pb   = (unsigned short*)(ws);            // [32768][1024] bf16
  unsigned short* dec  = (unsigned short*)(ws + 67108864);
  unsigned short* encb = (unsigned short*)(ws + 83886080);
  unsigned short* vtb  = (unsigned short*)(ws + 100663296);
  unsigned short* wcb  = (unsigned short*)(ws + 134217728);
  float*          rows = (float*)(ws + 134217728);         // reuses wcb post-conv
  unsigned short* mwb  = (unsigned short*)(ws + 135790592);
  unsigned short* awb  = (unsigned short*)(ws + 136052736);

  zero_k<<<1, 512, 0, stream>>>(dec);  // 1KB zero scratch for conv boundary
  cvt_bf16_k<<<8192, 256, 0, stream>>>(enc, encb, 32 * 1024 * 256);
  cvt_bf16_k<<<768, 256, 0, stream>>>(cw, wcb, 512 * 1536);
  cvt_bf16_k<<<128, 256, 0, stream>>>(mw, mwb, 512 * 256);
  cvt_bf16_k<<<128, 256, 0, stream>>>(aw, awb, 512 * 256);
  cvt_transpose_v_k<<<dim3(16, 8, 32), 256, 0, stream>>>(src, vtb);
  embed_affine_k<<<1024, 256, 0, stream>>>(target, emb, awb, ab, Xbf);
  conv_gemm_k<<<1024, 256, 0, stream>>>(Xbf, wcb, cb, dec, Ybf);
  zero_rows_k<<<32, 256, 0, stream>>>(rows);   // wcb dead after conv
  glu_k<<<8192, 256, 0, stream>>>(Ybf, dec);
  attn_s_k<<<2048, 256, 0, stream>>>(dec, encb, Pb, rows);
  attn_pv_k<<<1024, 256, 0, stream>>>(Pb, vtb, dec, mwb, rows, mb, out);
}

// Round 7
// 412.153 us; speedup vs baseline: 1.5771x; 1.0085x over previous
//
#include <hip/hip_runtime.h>
#include <stdint.h>

// ---------------------------------------------------------------------------
// Decoder block: emb-gather+affine -> causal conv(K=3) -> relu -> GLU(softmax)
//                -> map matmul (+) cross-attention (QK^T softmax PV)
// Shapes: V=50257 E=256 H=256 2H=512 K=3 T=1024 B=32 S=1024 L=1023
// R10: conv_gemm_k and attn_pv_k ported to a 256x256 8-wave phase-split
// schedule (T3+T4+T5 regime): BK=32, 4 LDS slots x 32KB (one K-step each,
// staging distance 2 -> margin 4 against overwrite), per K-step two
// {ds_read || stage-issue -> setprio MFMA -> barrier} phases, counted
// vmcnt(4) guard once per K-step (vmcnt(0) only at the last step).
// Full-XOR granule swizzle (g ^ row&3): frag reads optimal (8 lanes/bankgrp).
// attn_s (K=256 too short), embed, glu, cvts unchanged from R9.
// Workspace layout (bytes):
//   Xbf   [32][1024][512] bf16 @ 0          (33,554,432)  \ P [32768][1024]
//   Ybf   [32][1024][512] bf16 @ 33554432   (33,554,432)  / bf16 after glu
//   dec   [32][1024][256] bf16 @ 67108864   (first 1KB = conv zero scratch)
//   encb  [32][1024][256] bf16 @ 83886080
//   vtb   [32][512][1024] bf16 @ 100663296  (V transposed)
//   wcb   [512][1536]     bf16 @ 134217728  (first 128KB -> f32 rowsums)
//   mwb   [512][256]      bf16 @ 135790592
//   awb   [512][256]      bf16 @ 136052736
// ---------------------------------------------------------------------------

typedef __bf16 bf16x8_t __attribute__((ext_vector_type(8)));
typedef float  f32x4_t  __attribute__((ext_vector_type(4)));
typedef unsigned short u16x8 __attribute__((ext_vector_type(8)));

#define DEV __device__ __forceinline__

DEV unsigned short f2bf(float f) {
  union { float f; unsigned u; } v; v.f = f;
  unsigned r = v.u + 0x7fffu + ((v.u >> 16) & 1u);
  return (unsigned short)(r >> 16);
}
DEV float bf2f(unsigned short u) {
  union { unsigned u; float f; } v; v.u = ((unsigned)u) << 16;
  return v.f;
}

DEV void gload_lds16(const void* g, void* l) {
  __builtin_amdgcn_global_load_lds((const __attribute__((address_space(1))) void*)g,
                                   (__attribute__((address_space(3))) void*)l, 16, 0, 0);
}

DEV void vm_bar8() { asm volatile("s_waitcnt vmcnt(8)" ::: "memory"); __builtin_amdgcn_s_barrier(); }
DEV void vm_bar4() { asm volatile("s_waitcnt vmcnt(4)" ::: "memory"); __builtin_amdgcn_s_barrier(); }
DEV void vm_bar0() { asm volatile("s_waitcnt vmcnt(0)" ::: "memory"); __builtin_amdgcn_s_barrier(); }
DEV void lgkm_bar() { asm volatile("s_waitcnt lgkmcnt(0)" ::: "memory"); __builtin_amdgcn_s_barrier(); }

// ---------------- R9 3-stage BK32 pieces (used by attn_s_k) ----------------
DEV void stage32(unsigned short* Ld, int tid,
                 const unsigned short* a0, const unsigned short* a1,
                 const unsigned short* b0, const unsigned short* b1, int tt) {
  const int o = tt * 32;
  gload_lds16(a0 + o, Ld + tid * 8);
  gload_lds16(a1 + o, Ld + (tid + 256) * 8);
  gload_lds16(b0 + o, Ld + 4096 + tid * 8);
  gload_lds16(b1 + o, Ld + 4096 + (tid + 256) * 8);
}

DEV void gemm_step32(const unsigned short* Ld, int wr, int wc, int ln, int qsw,
                     f32x4_t (&acc)[4][4]) {
  bf16x8_t af[4], bff[4];
#pragma unroll
  for (int x = 0; x < 4; ++x) {
    af[x]  = *(const bf16x8_t*)(Ld + (wr * 64 + x * 16 + ln) * 32 + qsw);
    bff[x] = *(const bf16x8_t*)(Ld + 4096 + (wc * 64 + x * 16 + ln) * 32 + qsw);
  }
  __builtin_amdgcn_s_setprio(1);
#pragma unroll
  for (int mt = 0; mt < 4; ++mt)
#pragma unroll
    for (int nt = 0; nt < 4; ++nt)
      acc[mt][nt] = __builtin_amdgcn_mfma_f32_16x16x32_bf16(af[mt], bff[nt], acc[mt][nt], 0, 0, 0);
  __builtin_amdgcn_s_setprio(0);
}

// -------------------------- zero helpers -----------------------------------
__global__ void zero_k(unsigned short* p) { p[threadIdx.x] = 0; }

__global__ __launch_bounds__(256) void zero_rows_k(float* p) {
  int i = (blockIdx.x * 256 + threadIdx.x) * 4;
  *(float4*)(p + i) = make_float4(0.f, 0.f, 0.f, 0.f);
}

// -------------------------- f32 -> bf16 copy -------------------------------
__global__ __launch_bounds__(256) void cvt_bf16_k(const float* __restrict__ src,
                                                  unsigned short* __restrict__ dst,
                                                  int n) {
  int i = (blockIdx.x * 256 + threadIdx.x) * 4;
  if (i >= n) return;
  float4 v = *(const float4*)(src + i);
  ushort4 o;
  o.x = f2bf(v.x); o.y = f2bf(v.y); o.z = f2bf(v.z); o.w = f2bf(v.w);
  *(ushort4*)(dst + i) = o;
}

// ------------------- V: f32 [b][s][d] -> bf16 [b][d][s] --------------------
__global__ __launch_bounds__(256) void cvt_transpose_v_k(const float* __restrict__ src,
                                                         unsigned short* __restrict__ dst) {
  __shared__ float tile[64][65];
  const int b = blockIdx.z, s0 = blockIdx.x * 64, d0 = blockIdx.y * 64;
  const int tid = threadIdx.x;
  const int cs = (tid & 15) * 4;
  const int rs = tid >> 4;
  const float* p = src + ((size_t)b * 1024 + s0) * 512 + d0;
#pragma unroll
  for (int rr = 0; rr < 4; ++rr) {
    const int s = rs + rr * 16;
    float4 v = *(const float4*)(p + (size_t)s * 512 + cs);
    tile[s][cs] = v.x; tile[s][cs + 1] = v.y;
    tile[s][cs + 2] = v.z; tile[s][cs + 3] = v.w;
  }
  __syncthreads();
  const int ch = tid & 7;
  const int dd0 = tid >> 3;
#pragma unroll
  for (int it = 0; it < 2; ++it) {
    const int dd = dd0 + it * 32;
    u16x8 o;
#pragma unroll
    for (int j = 0; j < 8; ++j) o[j] = f2bf(tile[ch * 8 + j][dd]);
    *(u16x8*)(dst + ((size_t)b * 512 + d0 + dd) * 1024 + s0 + ch * 8) = o;
  }
}

// ------ X[b][t][c] = bf16( emb[target[t,b]] @ affine_w^T + affine_b ) ------
__global__ __launch_bounds__(256) void embed_affine_k(const int* __restrict__ tgt,
                                                      const float* __restrict__ emb,
                                                      const unsigned short* __restrict__ awb,
                                                      const float* __restrict__ ab,
                                                      unsigned short* __restrict__ X) {
  constexpr int AP = 264;
  __shared__ unsigned short xs[32 * AP];
  const int r0 = blockIdx.x * 32;
  const int tid = threadIdx.x;
  for (int idx = tid; idx < 32 * 64; idx += 256) {
    int r = idx >> 6, c4 = (idx & 63) * 4;
    int row = tgt[r0 + r];
    float4 v = *(const float4*)&emb[(size_t)row * 256 + c4];
    ushort4 o;
    o.x = f2bf(v.x); o.y = f2bf(v.y); o.z = f2bf(v.z); o.w = f2bf(v.w);
    *(ushort4*)&xs[r * AP + c4] = o;
  }
  __syncthreads();
  const int lane = tid & 63, w = tid >> 6, q = lane >> 4, ln = lane & 15;
  f32x4_t acc[2][8];
#pragma unroll
  for (int mt = 0; mt < 2; ++mt)
#pragma unroll
    for (int nt = 0; nt < 8; ++nt) acc[mt][nt] = (f32x4_t){0.f, 0.f, 0.f, 0.f};
  for (int kk = 0; kk < 256; kk += 32) {
    bf16x8_t a[2], bb[8];
#pragma unroll
    for (int mt = 0; mt < 2; ++mt)
      a[mt] = *(const bf16x8_t*)(xs + (mt * 16 + ln) * AP + kk + q * 8);
#pragma unroll
    for (int nt = 0; nt < 8; ++nt) {
      int n = ((w * 8 + nt) << 4) + ln;
      bb[nt] = *(const bf16x8_t*)(awb + ((size_t)n << 8) + kk + q * 8);
    }
#pragma unroll
    for (int mt = 0; mt < 2; ++mt)
#pragma unroll
      for (int nt = 0; nt < 8; ++nt)
        acc[mt][nt] = __builtin_amdgcn_mfma_f32_16x16x32_bf16(a[mt], bb[nt], acc[mt][nt], 0, 0, 0);
  }
#pragma unroll
  for (int nt = 0; nt < 8; ++nt) {
    const int o = ((w * 8 + nt) << 4) + ln;
    const float bias = ab[o];
#pragma unroll
    for (int mt = 0; mt < 2; ++mt)
#pragma unroll
      for (int r = 0; r < 4; ++r) {
        int rid = r0 + mt * 16 + q * 4 + r;
        int t = rid >> 5, b = rid & 31;
        X[(((size_t)(b * 1024 + t)) << 9) + o] = f2bf(acc[mt][nt][r] + bias);
      }
  }
}

// ---------------------------------------------------------------------------
// conv as 256x256 phase-split GEMM. K=1536 = 48 BK32 steps.
// A[l][k] = X[b][(l-2)+(k>>9)][k&511] -> flat (l-2)*512 + k (linear in k).
// Boundary (l0==0, staging rows 0,1): zbuf redirect while kt < tmin.
// 4 LDS slots x (A 256x32 + B 256x32) = 128KB; slot(kt)=kt&3; stage kt+2.
// ---------------------------------------------------------------------------
__global__ __launch_bounds__(512, 2) void conv_gemm_k(const unsigned short* __restrict__ X,
                                                      const unsigned short* __restrict__ Wc,
                                                      const float* __restrict__ cb,
                                                      const unsigned short* __restrict__ zbuf,
                                                      unsigned short* __restrict__ Y) {
  __shared__ unsigned short lds[4][16384];
  const int tid = threadIdx.x;
  const int w = tid >> 6, lane = tid & 63, ln = lane & 15, q = lane >> 4;
  const int wr = w >> 2, wc = w & 3;
  const int qsw = ((q ^ (ln & 3)) << 3);

  const int bid = blockIdx.x;            // 256 blocks; bid&7 -> XCD group
  const int xcd = bid & 7, j = bid >> 3;
  const int b = ((j >> 3) << 3) + xcd;   // 8 blocks per b share an XCD
  const int jj = j & 7;
  const int l0 = (jj >> 1) << 8;         // 0..768
  const int n0 = (jj & 1) << 8;          // 0 or 256

  // staging roles: 2 A granules (rows R, R+128) + 2 B granules per K-step
  const int R = tid >> 2, cg = tid & 3;
  const int sw = ((cg ^ (R & 3)) << 3);
  const unsigned short* aP0 = X + ((long)(b * 1024 + l0 + R - 2) * 512 + sw);
  const unsigned short* aP1 = aP0 + (long)128 * 512;
  const unsigned short* bP0 = Wc + ((long)(n0 + R) * 1536 + sw);
  const unsigned short* bP1 = bP0 + (long)128 * 1536;
  const int tmin0 = (l0 == 0) ? (R == 0 ? 32 : (R == 1 ? 16 : 0)) : 0;

  auto STGA = [&](int tkt) {
    unsigned short* Ld = lds[tkt & 3];
    const unsigned short* s0 = (tkt >= tmin0) ? (aP0 + tkt * 32) : (zbuf + sw);
    gload_lds16(s0, Ld + tid * 8);
    gload_lds16(aP1 + tkt * 32, Ld + 4096 + tid * 8);
  };
  auto STGB = [&](int tkt) {
    unsigned short* Ld = lds[tkt & 3];
    gload_lds16(bP0 + tkt * 32, Ld + 8192 + tid * 8);
    gload_lds16(bP1 + tkt * 32, Ld + 12288 + tid * 8);
  };

  f32x4_t acc[8][4];
#pragma unroll
  for (int mt = 0; mt < 8; ++mt)
#pragma unroll
    for (int nt = 0; nt < 4; ++nt) acc[mt][nt] = (f32x4_t){0.f, 0.f, 0.f, 0.f};

  STGA(0); STGB(0); STGA(1); STGB(1);

  for (int kt = 0; kt < 48; ++kt) {
    // guard: slot kt&3 fully landed (stage(kt+1)'s 4 loads may stay in flight)
    if (kt < 47) asm volatile("s_waitcnt vmcnt(4)" ::: "memory");
    else         asm volatile("s_waitcnt vmcnt(0)" ::: "memory");
    __builtin_amdgcn_s_barrier();
    const unsigned short* Ld = lds[kt & 3];
    bf16x8_t af[4], bff[4];
    // ---- phase 0: mf 0-3 x nf 0-3 ----
#pragma unroll
    for (int x = 0; x < 4; ++x) {
      af[x]  = *(const bf16x8_t*)(Ld + (wr * 128 + x * 16 + ln) * 32 + qsw);
      bff[x] = *(const bf16x8_t*)(Ld + 8192 + (wc * 64 + x * 16 + ln) * 32 + qsw);
    }
    if (kt < 46) STGA(kt + 2);
    __builtin_amdgcn_s_setprio(1);
#pragma unroll
    for (int mt = 0; mt < 4; ++mt)
#pragma unroll
      for (int nt = 0; nt < 4; ++nt)
        acc[mt][nt] = __builtin_amdgcn_mfma_f32_16x16x32_bf16(af[mt], bff[nt], acc[mt][nt], 0, 0, 0);
    __builtin_amdgcn_s_setprio(0);
    __builtin_amdgcn_s_barrier();
    // ---- phase 1: mf 4-7 x nf 0-3 (B reused in regs) ----
#pragma unroll
    for (int x = 0; x < 4; ++x)
      af[x] = *(const bf16x8_t*)(Ld + (wr * 128 + 64 + x * 16 + ln) * 32 + qsw);
    if (kt < 46) STGB(kt + 2);
    __builtin_amdgcn_s_setprio(1);
#pragma unroll
    for (int mt = 0; mt < 4; ++mt)
#pragma unroll
      for (int nt = 0; nt < 4; ++nt)
        acc[4 + mt][nt] = __builtin_amdgcn_mfma_f32_16x16x32_bf16(af[mt], bff[nt], acc[4 + mt][nt], 0, 0, 0);
    __builtin_amdgcn_s_setprio(0);
    __builtin_amdgcn_s_barrier();
  }

#pragma unroll
  for (int nt = 0; nt < 4; ++nt) {
    const int o = n0 + wc * 64 + nt * 16 + ln;
    const float bias = cb[o];
#pragma unroll
    for (int mt = 0; mt < 8; ++mt)
#pragma unroll
      for (int r = 0; r < 4; ++r) {
        const int l = l0 + wr * 128 + mt * 16 + q * 4 + r;
        float v = acc[mt][nt][r] + bias;
        Y[(((size_t)b * 1024 + l) << 9) + o] = f2bf(v > 0.f ? v : 0.f);
      }
  }
}

// ---- GLU: dec[b][l][h] = A[h] * softmax_h(Bg)[h], one wave per (b,l) row ---
__global__ __launch_bounds__(256) void glu_k(const unsigned short* __restrict__ Y,
                                             unsigned short* __restrict__ dec) {
  const int row = blockIdx.x * 4 + (threadIdx.x >> 6);
  const int lane = threadIdx.x & 63;
  const unsigned short* p = Y + ((size_t)row << 9);
  ushort4 av = *(const ushort4*)(p + lane * 4);
  ushort4 gv = *(const ushort4*)(p + 256 + lane * 4);
  float e0 = __expf(bf2f(gv.x)), e1 = __expf(bf2f(gv.y));
  float e2 = __expf(bf2f(gv.z)), e3 = __expf(bf2f(gv.w));
  float s = e0 + e1 + e2 + e3;
#pragma unroll
  for (int off = 32; off > 0; off >>= 1) s += __shfl_xor(s, off);
  float inv = 1.f / s;
  ushort4 o;
  o.x = f2bf(bf2f(av.x) * e0 * inv);
  o.y = f2bf(bf2f(av.y) * e1 * inv);
  o.z = f2bf(bf2f(av.z) * e2 * inv);
  o.w = f2bf(bf2f(av.w) * e3 * inv);
  *(ushort4*)(dec + ((size_t)row << 8) + lane * 4) = o;
}

// ---------------------------------------------------------------------------
// attn GEMM1 (unchanged R9 3-stage): P = exp(dec @ enc^T), rowsum atomics.
// ---------------------------------------------------------------------------
__global__ __launch_bounds__(256, 3) void attn_s_k(const unsigned short* __restrict__ dec,
                                                   const unsigned short* __restrict__ enc,
                                                   unsigned short* __restrict__ P,
                                                   float* __restrict__ rows) {
  __shared__ unsigned short tb[3][8192];
  const int bid = blockIdx.x;
  const int wg = ((bid & 7) << 8) + (bid >> 3);
  const int ntile = wg & 7, mtile = wg >> 3;
  const int b = mtile >> 3;
  const int row0 = mtile << 7;
  const int s0 = ntile << 7;
  const int tid = threadIdx.x;
  const int w = tid >> 6, lane = tid & 63, q = lane >> 4, ln = lane & 15;
  const int wr = w >> 1, wc = w & 1;
  const int qsw = (q ^ (ln & 3)) << 3;

  const int r0g = tid >> 2, r1g = (tid + 256) >> 2;
  const int cg = tid & 3;
  const int c0g = ((cg ^ (r0g & 3)) << 3);
  const int c1g = ((cg ^ (r1g & 3)) << 3);

  const unsigned short* Ab = dec + ((size_t)row0 << 8);
  const unsigned short* Bb = enc + ((size_t)b << 18) + ((size_t)s0 << 8);
  const unsigned short* a0 = Ab + (size_t)r0g * 256 + c0g;
  const unsigned short* a1 = Ab + (size_t)r1g * 256 + c1g;
  const unsigned short* b0 = Bb + (size_t)r0g * 256 + c0g;
  const unsigned short* b1 = Bb + (size_t)r1g * 256 + c1g;

  f32x4_t acc[4][4];
#pragma unroll
  for (int mt = 0; mt < 4; ++mt)
#pragma unroll
    for (int nt = 0; nt < 4; ++nt) acc[mt][nt] = (f32x4_t){0.f, 0.f, 0.f, 0.f};

  unsigned short *p0 = tb[0], *p1 = tb[1], *p2 = tb[2];
  stage32(p0, tid, a0, a1, b0, b1, 0);
  stage32(p1, tid, a0, a1, b0, b1, 1);

  for (int t = 0; t < 8; ++t) {
    if (t + 2 < 8) { stage32(p2, tid, a0, a1, b0, b1, t + 2); vm_bar8(); }
    else if (t + 1 < 8) vm_bar4();
    else vm_bar0();
    gemm_step32(p0, wr, wc, ln, qsw, acc);
    lgkm_bar();
    unsigned short* tmp = p0; p0 = p1; p1 = p2; p2 = tmp;
  }

  float rs[4][4];
#pragma unroll
  for (int mt = 0; mt < 4; ++mt)
#pragma unroll
    for (int r = 0; r < 4; ++r) rs[mt][r] = 0.f;
#pragma unroll
  for (int nt = 0; nt < 4; ++nt) {
    const int col = s0 + wc * 64 + nt * 16 + ln;
#pragma unroll
    for (int mt = 0; mt < 4; ++mt)
#pragma unroll
      for (int r = 0; r < 4; ++r) {
        const int row = row0 + wr * 64 + mt * 16 + q * 4 + r;
        float e = __expf(acc[mt][nt][r]);
        rs[mt][r] += e;
        P[((size_t)row << 10) + col] = f2bf(e);
      }
  }
#pragma unroll
  for (int mt = 0; mt < 4; ++mt)
#pragma unroll
    for (int r = 0; r < 4; ++r) {
      float v = rs[mt][r];
      v += __shfl_xor(v, 1); v += __shfl_xor(v, 2);
      v += __shfl_xor(v, 4); v += __shfl_xor(v, 8);
      if (ln == 0)
        atomicAdd(&rows[row0 + wr * 64 + mt * 16 + q * 4 + r], v);
    }
}

// ---------------------------------------------------------------------------
// attn GEMM2 as 256x256 phase-split GEMM. NK = 40 BK32 steps:
// kt 0-31: PV (P [row][1024] x vt [d][1024]); kt 32-39: map chunk
// (dec [row][256] x mwb [d][256]); rinv scale between kt 31 and 32.
// rinv loaded BEFORE prologue staging (oldest in vm FIFO -> guards stay valid)
// ---------------------------------------------------------------------------
__global__ __launch_bounds__(512, 2) void attn_pv_k(const unsigned short* __restrict__ P,
                                                    const unsigned short* __restrict__ vt,
                                                    const unsigned short* __restrict__ dec,
                                                    const unsigned short* __restrict__ mw,
                                                    const float* __restrict__ rows,
                                                    const float* __restrict__ mb,
                                                    float* __restrict__ out) {
  __shared__ unsigned short lds[4][16384];
  const int tid = threadIdx.x;
  const int w = tid >> 6, lane = tid & 63, ln = lane & 15, q = lane >> 4;
  const int wr = w >> 2, wc = w & 3;
  const int qsw = ((q ^ (ln & 3)) << 3);

  const int bid = blockIdx.x;            // 256 blocks
  const int xcd = bid & 7, j = bid >> 3;
  const int b = ((j >> 3) << 3) + xcd;
  const int jj = j & 7;
  const int row0 = b * 1024 + ((jj >> 1) << 8);
  const int d0 = (jj & 1) << 8;

  const int R = tid >> 2, cg = tid & 3;
  const int sw = ((cg ^ (R & 3)) << 3);
  const unsigned short* a1P0 = P + ((long)(row0 + R) * 1024 + sw);
  const unsigned short* a1P1 = a1P0 + (long)128 * 1024;
  const unsigned short* b1P0 = vt + ((long)b << 19) + ((long)(d0 + R) * 1024 + sw);
  const unsigned short* b1P1 = b1P0 + (long)128 * 1024;
  const unsigned short* a2P0 = dec + ((long)(row0 + R) * 256 + sw);
  const unsigned short* a2P1 = a2P0 + (long)128 * 256;
  const unsigned short* b2P0 = mw + ((long)(d0 + R) * 256 + sw);
  const unsigned short* b2P1 = b2P0 + (long)128 * 256;

  auto STGA = [&](int tkt) {
    unsigned short* Ld = lds[tkt & 3];
    if (tkt < 32) {
      gload_lds16(a1P0 + tkt * 32, Ld + tid * 8);
      gload_lds16(a1P1 + tkt * 32, Ld + 4096 + tid * 8);
    } else {
      gload_lds16(a2P0 + (tkt - 32) * 32, Ld + tid * 8);
      gload_lds16(a2P1 + (tkt - 32) * 32, Ld + 4096 + tid * 8);
    }
  };
  auto STGB = [&](int tkt) {
    unsigned short* Ld = lds[tkt & 3];
    if (tkt < 32) {
      gload_lds16(b1P0 + tkt * 32, Ld + 8192 + tid * 8);
      gload_lds16(b1P1 + tkt * 32, Ld + 12288 + tid * 8);
    } else {
      gload_lds16(b2P0 + (tkt - 32) * 32, Ld + 8192 + tid * 8);
      gload_lds16(b2P1 + (tkt - 32) * 32, Ld + 12288 + tid * 8);
    }
  };

  // rinv first: oldest entries in the vm FIFO, retired by the first guard.
  float rinv[8][4];
#pragma unroll
  for (int mt = 0; mt < 8; ++mt)
#pragma unroll
    for (int r = 0; r < 4; ++r)
      rinv[mt][r] = 1.f / rows[row0 + wr * 128 + mt * 16 + q * 4 + r];

  f32x4_t acc[8][4];
#pragma unroll
  for (int mt = 0; mt < 8; ++mt)
#pragma unroll
    for (int nt = 0; nt < 4; ++nt) acc[mt][nt] = (f32x4_t){0.f, 0.f, 0.f, 0.f};

  STGA(0); STGB(0); STGA(1); STGB(1);

  for (int kt = 0; kt < 40; ++kt) {
    if (kt < 39) asm volatile("s_waitcnt vmcnt(4)" ::: "memory");
    else         asm volatile("s_waitcnt vmcnt(0)" ::: "memory");
    __builtin_amdgcn_s_barrier();
    const unsigned short* Ld = lds[kt & 3];
    bf16x8_t af[4], bff[4];
    // ---- phase 0 ----
#pragma unroll
    for (int x = 0; x < 4; ++x) {
      af[x]  = *(const bf16x8_t*)(Ld + (wr * 128 + x * 16 + ln) * 32 + qsw);
      bff[x] = *(const bf16x8_t*)(Ld + 8192 + (wc * 64 + x * 16 + ln) * 32 + qsw);
    }
    if (kt < 38) STGA(kt + 2);
    __builtin_amdgcn_s_setprio(1);
#pragma unroll
    for (int mt = 0; mt < 4; ++mt)
#pragma unroll
      for (int nt = 0; nt < 4; ++nt)
        acc[mt][nt] = __builtin_amdgcn_mfma_f32_16x16x32_bf16(af[mt], bff[nt], acc[mt][nt], 0, 0, 0);
    __builtin_amdgcn_s_setprio(0);
    __builtin_amdgcn_s_barrier();
    // ---- phase 1 ----
#pragma unroll
    for (int x = 0; x < 4; ++x)
      af[x] = *(const bf16x8_t*)(Ld + (wr * 128 + 64 + x * 16 + ln) * 32 + qsw);
    if (kt < 38) STGB(kt + 2);
    __builtin_amdgcn_s_setprio(1);
#pragma unroll
    for (int mt = 0; mt < 4; ++mt)
#pragma unroll
      for (int nt = 0; nt < 4; ++nt)
        acc[4 + mt][nt] = __builtin_amdgcn_mfma_f32_16x16x32_bf16(af[mt], bff[nt], acc[4 + mt][nt], 0, 0, 0);
    __builtin_amdgcn_s_setprio(0);
    __builtin_amdgcn_s_barrier();
    if (kt == 31) {
      // PV done: normalize by rowsum before the map chunk accumulates
#pragma unroll
      for (int mt = 0; mt < 8; ++mt)
#pragma unroll
        for (int nt = 0; nt < 4; ++nt)
#pragma unroll
          for (int r = 0; r < 4; ++r) acc[mt][nt][r] *= rinv[mt][r];
    }
  }

  // epilogue: + bias, store f32, skip l == 1023
#pragma unroll
  for (int nt = 0; nt < 4; ++nt) {
    const int d = d0 + wc * 64 + nt * 16 + ln;
    const float bias = mb[d];
#pragma unroll
    for (int mt = 0; mt < 8; ++mt)
#pragma unroll
      for (int r = 0; r < 4; ++r) {
        const int row = row0 + wr * 128 + mt * 16 + q * 4 + r;
        const int l = row & 1023;
        if (l < 1023)
          out[((size_t)b * 1023 + l) * 512 + d] = acc[mt][nt][r] + bias;
      }
  }
}

// ---------------------------------------------------------------------------
extern "C" void kernel_launch(void* const* d_in, const int* in_sizes, int n_in,
                              void* d_out, int out_size, void* d_ws, size_t ws_size,
                              hipStream_t stream) {
  const int*   target = (const int*)d_in[1];
  const float* enc    = (const float*)d_in[2];
  const float* src    = (const float*)d_in[3];
  const float* emb    = (const float*)d_in[4];
  const float* aw     = (const float*)d_in[5];
  const float* ab     = (const float*)d_in[6];
  const float* cw     = (const float*)d_in[7];
  const float* cb     = (const float*)d_in[8];
  const float* mw     = (const float*)d_in[9];
  const float* mb     = (const float*)d_in[10];
  float* out = (float*)d_out;
  char* ws = (char*)d_ws;

  unsigned short* Xbf  = (unsigned short*)(ws);            // P aliases Xbf+Ybf
  unsigned short* Ybf  = (unsigned short*)(ws + 33554432);
  unsigned short* Pb   = (unsigned short*)(ws);            // [32768][1024] bf16
  unsigned short* dec  = (unsigned short*)(ws + 67108864);
  unsigned short* encb = (unsigned short*)(ws + 83886080);
  unsigned short* vtb  = (unsigned short*)(ws + 100663296);
  unsigned short* wcb  = (unsigned short*)(ws + 134217728);
  float*          rows = (float*)(ws + 134217728);         // reuses wcb post-conv
  unsigned short* mwb  = (unsigned short*)(ws + 135790592);
  unsigned short* awb  = (unsigned short*)(ws + 136052736);

  zero_k<<<1, 512, 0, stream>>>(dec);  // 1KB zero scratch for conv boundary
  cvt_bf16_k<<<8192, 256, 0, stream>>>(enc, encb, 32 * 1024 * 256);
  cvt_bf16_k<<<768, 256, 0, stream>>>(cw, wcb, 512 * 1536);
  cvt_bf16_k<<<128, 256, 0, stream>>>(mw, mwb, 512 * 256);
  cvt_bf16_k<<<128, 256, 0, stream>>>(aw, awb, 512 * 256);
  cvt_transpose_v_k<<<dim3(16, 8, 32), 256, 0, stream>>>(src, vtb);
  embed_affine_k<<<1024, 256, 0, stream>>>(target, emb, awb, ab, Xbf);
  conv_gemm_k<<<256, 512, 0, stream>>>(Xbf, wcb, cb, dec, Ybf);
  zero_rows_k<<<32, 256, 0, stream>>>(rows);   // wcb dead after conv
  glu_k<<<8192, 256, 0, stream>>>(Ybf, dec);
  attn_s_k<<<2048, 256, 0, stream>>>(dec, encb, Pb, rows);
  attn_pv_k<<<256, 512, 0, stream>>>(Pb, vtb, dec, mwb, rows, mb, out);
}